// Round 6
// baseline (2651.337 us; speedup 1.0000x reference)
//
#include <hip/hip_runtime.h>
#include <hip/hip_bf16.h>

#define STC_N     5000
#define STC_TIN   16
#define STC_T1    14
#define STC_T2    12
#define STC_CIN   16
#define STC_CH    32
#define STC_CO    64
#define STC_BT1   56
#define STC_BT2   48
#define STC_ROWS1 280000
#define STC_ROWS2 240000

#define STC_OFF_DEG   0
#define STC_OFF_CNT   20000
#define STC_OFF_CUR   40000
#define STC_OFF_DIS   60000
#define STC_OFF_OFFS  80000
#define STC_OFF_WN    100032
#define STC_OFF_CCOL  420032
#define STC_OFF_CW    740032
#define STC_OFF_T0    1060096
#define STC_OFF_G1    (STC_OFF_T0 + 17920000)
#define STC_OFF_G2    (STC_OFF_G1 + 17920000)
#define STC_WS_REQ    (STC_OFF_G2 + 17920000)

typedef __hip_bfloat16 bf16;

__device__ float stc_b2f(bf16 v) { return __bfloat162float(v); }

__global__ void STConv_9972914061616_kernel() {}

__global__ void stc_fill(float* out, int n, float val) {
    int i = blockIdx.x * 256 + threadIdx.x;
    if (i < n) out[i] = val;
}

__global__ void stc_zero(int* p, int n) {
    int i = blockIdx.x * 256 + threadIdx.x;
    if (i < n) p[i] = 0;
}

__global__ void stc_deg(const int* ei, const float* ew, float* deg, int E) {
    int e = blockIdx.x * 256 + threadIdx.x;
    if (e < E) atomicAdd(&deg[ei[e]], ew[e]);
}

__global__ void stc_dis(const float* deg, float* dis, int n) {
    int i = blockIdx.x * 256 + threadIdx.x;
    if (i < n) {
        float d = deg[i];
        dis[i] = (d > 0.0f) ? rsqrtf(d) : 0.0f;
    }
}

__global__ void stc_wnorm(const int* ei, const float* ew, const float* dis,
                          float* wn, int* cnt, int E) {
    int e = blockIdx.x * 256 + threadIdx.x;
    if (e < E) {
        int r = ei[e];
        int c = ei[E + e];
        wn[e] = dis[r] * ew[e] * dis[c];
        atomicAdd(&cnt[r], 1);
    }
}

__global__ void stc_scan(const int* cnt, int* offs, int n) {
    __shared__ int s[256];
    __shared__ int carry;
    if (threadIdx.x == 0) carry = 0;
    __syncthreads();
    for (int base = 0; base < n; base += 256) {
        int i = base + threadIdx.x;
        int v = (i < n) ? cnt[i] : 0;
        s[threadIdx.x] = v;
        __syncthreads();
        for (int off = 1; off < 256; off <<= 1) {
            int t = (threadIdx.x >= off) ? s[threadIdx.x - off] : 0;
            __syncthreads();
            s[threadIdx.x] += t;
            __syncthreads();
        }
        int c0 = carry;
        if (i < n) offs[i] = c0 + s[threadIdx.x] - v;
        __syncthreads();
        if (threadIdx.x == 0) carry = c0 + s[255];
        __syncthreads();
    }
    if (threadIdx.x == 0) offs[n] = carry;
}

__global__ void stc_scatter(const int* ei, const float* wn, const int* offs,
                            int* cursor, int* ccol, float* cw, int E) {
    int e = blockIdx.x * 256 + threadIdx.x;
    if (e < E) {
        int r = ei[e];
        int pos = atomicAdd(&cursor[r], 1);
        int slot = offs[r] + pos;
        ccol[slot] = ei[E + e];
        cw[slot] = wn[e];
    }
}

/* (B,16,N,16)f32 -> (B,14,N,32)bf16: 8 rows x 32 outch per block */
__global__ void stc_tconv1(const float* X,
                           const float* W1, const float* B1,
                           const float* W2, const float* B2,
                           const float* W3, const float* B3,
                           bf16* T0) {
    __shared__ float wl[3][48][32];
    __shared__ float bl[3][32];
    for (int conv = 0; conv < 3; ++conv) {
        const float* Wp = (conv == 0) ? W1 : ((conv == 1) ? W2 : W3);
        for (int i = threadIdx.x; i < 1536; i += 256) {
            int o = i & 31;
            int ck = i >> 5;
            wl[conv][ck][o] = Wp[o * 48 + ck];
        }
    }
    if (threadIdx.x < 96) {
        int conv = threadIdx.x >> 5;
        int o = threadIdx.x & 31;
        const float* Bp = (conv == 0) ? B1 : ((conv == 1) ? B2 : B3);
        bl[conv][o] = Bp[o];
    }
    __syncthreads();

    int r = blockIdx.x * 8 + (threadIdx.x >> 5);
    int o = threadIdx.x & 31;
    if (r >= STC_ROWS1) return;
    int n = r % STC_N;
    int bt = r / STC_N;
    int t = bt % STC_T1;
    int b = bt / STC_T1;

    float P = bl[0][o];
    float Q = bl[1][o];
    float R = bl[2][o];
    for (int k = 0; k < 3; ++k) {
        const float* xp = X + ((size_t)((b * STC_TIN + t + k) * STC_N + n)) * STC_CIN;
        for (int c = 0; c < STC_CIN; ++c) {
            float x = xp[c];
            int ck = c * 3 + k;
            P += x * wl[0][ck][o];
            Q += x * wl[1][ck][o];
            R += x * wl[2][ck][o];
        }
    }
    float Qc = fminf(fmaxf(Q, -30.0f), 30.0f);
    float sg = 1.0f / (1.0f + expf(-Qc));
    float h = P * sg + R;
    if (h < 0.0f) h = 0.0f;
    T0[((size_t)bt * STC_N + n) * STC_CH + o] = __float2bfloat16(h);
}

/* g[bt,n,:] = sum_{e: row==n} w[e] * z[bt,col[e],:]  (z,g: (56,N,32) bf16) */
__global__ void stc_gather(const bf16* z, bf16* g, const int* offs,
                           const int* ccol, const float* cw) {
    int n = blockIdx.x;
    __shared__ int col_s[128];
    __shared__ float w_s[128];
    int beg = offs[n];
    int end = offs[n + 1];
    int p = threadIdx.x >> 5;
    int c = threadIdx.x & 31;
    float a0 = 0.0f, a1 = 0.0f, a2 = 0.0f, a3 = 0.0f, a4 = 0.0f, a5 = 0.0f, a6 = 0.0f;
    for (int chunk = beg; chunk < end; chunk += 128) {
        int m = end - chunk;
        if (m > 128) m = 128;
        if (threadIdx.x < m) {
            col_s[threadIdx.x] = ccol[chunk + threadIdx.x];
            w_s[threadIdx.x] = cw[chunk + threadIdx.x];
        }
        __syncthreads();
        for (int i = 0; i < m; ++i) {
            float w = w_s[i];
            const bf16* zp = z + (size_t)col_s[i] * STC_CH + c;
            size_t st = (size_t)STC_N * STC_CH;
            a0 += w * stc_b2f(zp[(p +  0) * st]);
            a1 += w * stc_b2f(zp[(p +  8) * st]);
            a2 += w * stc_b2f(zp[(p + 16) * st]);
            a3 += w * stc_b2f(zp[(p + 24) * st]);
            a4 += w * stc_b2f(zp[(p + 32) * st]);
            a5 += w * stc_b2f(zp[(p + 40) * st]);
            a6 += w * stc_b2f(zp[(p + 48) * st]);
        }
        __syncthreads();
    }
    size_t go = (size_t)n * STC_CH + c;
    size_t gs = (size_t)STC_N * STC_CH;
    g[go + (p +  0) * gs] = __float2bfloat16(a0);
    g[go + (p +  8) * gs] = __float2bfloat16(a1);
    g[go + (p + 16) * gs] = __float2bfloat16(a2);
    g[go + (p + 24) * gs] = __float2bfloat16(a3);
    g[go + (p + 32) * gs] = __float2bfloat16(a4);
    g[go + (p + 40) * gs] = __float2bfloat16(a5);
    g[go + (p + 48) * gs] = __float2bfloat16(a6);
}

/* Tch = relu(T0*(W0-W2) - G1*W1 + 2*G2*W2 + b); out aliases T0 (per-wave
   read-before-write; rows disjoint across waves; no __restrict__ anywhere) */
__global__ void stc_combine(const bf16* Tx0, const bf16* G1, const bf16* G2,
                            const float* W, const float* bias, bf16* out) {
    __shared__ float wm[3][32][32];
    __shared__ float bl[32];
    for (int i = threadIdx.x; i < 1024; i += 256) {
        float w0 = W[i];
        float w1 = W[1024 + i];
        float w2 = W[2048 + i];
        int c = i >> 5;
        int d = i & 31;
        wm[0][c][d] = w0 - w2;
        wm[1][c][d] = -w1;
        wm[2][c][d] = 2.0f * w2;
    }
    if (threadIdx.x < 32) bl[threadIdx.x] = bias[threadIdx.x];
    __syncthreads();

    int r = blockIdx.x * 8 + (threadIdx.x >> 5);
    int d = threadIdx.x & 31;
    if (r >= STC_ROWS1) return;
    size_t base = (size_t)r * STC_CH;
    float acc = bl[d];
    for (int c = 0; c < STC_CH; ++c) {
        acc += stc_b2f(Tx0[base + c]) * wm[0][c][d];
        acc += stc_b2f(G1[base + c]) * wm[1][c][d];
        acc += stc_b2f(G2[base + c]) * wm[2][c][d];
    }
    if (acc < 0.0f) acc = 0.0f;
    out[base + d] = __float2bfloat16(acc);
}

/* (B,14,N,32)bf16 -> (B,12,N,64)f32 (staged in d_out): 4 rows x 64 outch */
__global__ void stc_tconv2(const bf16* Tch,
                           const float* W1, const float* B1,
                           const float* W2, const float* B2,
                           const float* W3, const float* B3,
                           float* T2) {
    __shared__ bf16 wl[3][96][64];   /* 36.9 KB */
    __shared__ float bl[3][64];
    for (int conv = 0; conv < 3; ++conv) {
        const float* Wp = (conv == 0) ? W1 : ((conv == 1) ? W2 : W3);
        for (int i = threadIdx.x; i < 6144; i += 256) {
            int o = i & 63;
            int ck = i >> 6;
            wl[conv][ck][o] = __float2bfloat16(Wp[o * 96 + ck]);
        }
        const float* Bp = (conv == 0) ? B1 : ((conv == 1) ? B2 : B3);
        if (threadIdx.x < 64) bl[conv][threadIdx.x] = Bp[threadIdx.x];
    }
    __syncthreads();

    int r = blockIdx.x * 4 + (threadIdx.x >> 6);
    int o = threadIdx.x & 63;
    if (r >= STC_ROWS2) return;
    int n = r % STC_N;
    int bt = r / STC_N;
    int t = bt % STC_T2;
    int b = bt / STC_T2;

    float P = bl[0][o];
    float Q = bl[1][o];
    float R = bl[2][o];
    for (int k = 0; k < 3; ++k) {
        const bf16* xp = Tch + ((size_t)((b * STC_T1 + t + k) * STC_N + n)) * STC_CH;
        for (int c = 0; c < STC_CH; ++c) {
            float x = stc_b2f(xp[c]);
            int ck = c * 3 + k;
            P += x * stc_b2f(wl[0][ck][o]);
            Q += x * stc_b2f(wl[1][ck][o]);
            R += x * stc_b2f(wl[2][ck][o]);
        }
    }
    float Qc = fminf(fmaxf(Q, -30.0f), 30.0f);
    float sg = 1.0f / (1.0f + expf(-Qc));
    float h = P * sg + R;
    if (h < 0.0f) h = 0.0f;
    T2[((size_t)bt * STC_N + n) * STC_CO + o] = h;
}

/* per-node batch norm over (B,T,C), in-place on d_out (f32).
   If stats are non-finite, emit flag value 7.0 (diagnostic channel). */
__global__ void stc_bn(float* T2, const float* gamma, const float* beta) {
    int n = blockIdx.x;
    __shared__ float buf[STC_BT2 * STC_CO];
    __shared__ float red[256];
    float s = 0.0f;
    for (int i = threadIdx.x; i < STC_BT2 * STC_CO; i += 256) {
        int p = i >> 6;
        int c = i & 63;
        float v = T2[((size_t)p * STC_N + n) * STC_CO + c];
        buf[i] = v;
        s += v;
    }
    red[threadIdx.x] = s;
    __syncthreads();
    for (int off = 128; off > 0; off >>= 1) {
        if (threadIdx.x < off) red[threadIdx.x] += red[threadIdx.x + off];
        __syncthreads();
    }
    float mean = red[0] * (1.0f / (STC_BT2 * STC_CO));
    __syncthreads();
    float sq = 0.0f;
    for (int i = threadIdx.x; i < STC_BT2 * STC_CO; i += 256) {
        float d = buf[i] - mean;
        sq += d * d;
    }
    red[threadIdx.x] = sq;
    __syncthreads();
    for (int off = 128; off > 0; off >>= 1) {
        if (threadIdx.x < off) red[threadIdx.x] += red[threadIdx.x + off];
        __syncthreads();
    }
    float var = red[0] * (1.0f / (STC_BT2 * STC_CO));
    int bad = !(fabsf(mean) < 1e30f) || !(fabsf(var) < 1e30f);
    float istd = rsqrtf(var + 1e-5f);
    float scale = istd * gamma[n];
    float shift = beta[n] - mean * scale;
    for (int i = threadIdx.x; i < STC_BT2 * STC_CO; i += 256) {
        int p = i >> 6;
        int c = i & 63;
        float v = bad ? 7.0f : (buf[i] * scale + shift);
        T2[((size_t)p * STC_N + n) * STC_CO + c] = v;
    }
}

extern "C" void kernel_launch(void* const* d_in, const int* in_sizes, int n_in,
                              void* d_out, int out_size, void* d_ws, size_t ws_size,
                              hipStream_t stream) {
    float* out = (float*)d_out;
    int outb = (out_size + 255) / 256;

    if (n_in < 19) {
        stc_fill<<<outb, 256, 0, stream>>>(out, out_size, 60.0f);
        return;
    }
    if (ws_size < (size_t)STC_WS_REQ) {
        stc_fill<<<outb, 256, 0, stream>>>(out, out_size, 50.0f);
        return;
    }

    const float* X = (const float*)d_in[0];
    const int* ei = (const int*)d_in[1];
    const float* ew = (const float*)d_in[2];
    const float* w1a = (const float*)d_in[3];
    const float* b1a = (const float*)d_in[4];
    const float* w1b = (const float*)d_in[5];
    const float* b1b = (const float*)d_in[6];
    const float* w1c = (const float*)d_in[7];
    const float* b1c = (const float*)d_in[8];
    const float* chW = (const float*)d_in[9];
    const float* chB = (const float*)d_in[10];
    const float* w2a = (const float*)d_in[11];
    const float* b2a = (const float*)d_in[12];
    const float* w2b = (const float*)d_in[13];
    const float* b2b = (const float*)d_in[14];
    const float* w2c = (const float*)d_in[15];
    const float* b2c = (const float*)d_in[16];
    const float* gam = (const float*)d_in[17];
    const float* bet = (const float*)d_in[18];
    int E = in_sizes[1] / 2;

    char* ws = (char*)d_ws;
    float* deg = (float*)(ws + STC_OFF_DEG);
    int* cnt = (int*)(ws + STC_OFF_CNT);
    int* cursor = (int*)(ws + STC_OFF_CUR);
    float* dis = (float*)(ws + STC_OFF_DIS);
    int* offs = (int*)(ws + STC_OFF_OFFS);
    float* wn = (float*)(ws + STC_OFF_WN);
    int* ccol = (int*)(ws + STC_OFF_CCOL);
    float* cw = (float*)(ws + STC_OFF_CW);
    bf16* T0 = (bf16*)(ws + STC_OFF_T0);
    bf16* G1 = (bf16*)(ws + STC_OFF_G1);
    bf16* G2 = (bf16*)(ws + STC_OFF_G2);
    bf16* Tch = T0;          /* alias: per-wave read-before-write safe */
    float* T2 = out;         /* stage tconv2 output in d_out; BN in-place */

    stc_zero<<<59, 256, 0, stream>>>((int*)(ws + STC_OFF_DEG), 15000);
    stc_deg<<<(E + 255) / 256, 256, 0, stream>>>(ei, ew, deg, E);
    stc_dis<<<20, 256, 0, stream>>>(deg, dis, STC_N);
    stc_wnorm<<<(E + 255) / 256, 256, 0, stream>>>(ei, ew, dis, wn, cnt, E);
    stc_scan<<<1, 256, 0, stream>>>(cnt, offs, STC_N);
    stc_scatter<<<(E + 255) / 256, 256, 0, stream>>>(ei, wn, offs, cursor, ccol, cw, E);
    stc_tconv1<<<STC_ROWS1 / 8, 256, 0, stream>>>(X, w1a, b1a, w1b, b1b, w1c, b1c, T0);
    stc_gather<<<STC_N, 256, 0, stream>>>(T0, G1, offs, ccol, cw);
    stc_gather<<<STC_N, 256, 0, stream>>>(G1, G2, offs, ccol, cw);
    stc_combine<<<STC_ROWS1 / 8, 256, 0, stream>>>(T0, G1, G2, chW, chB, Tch);
    stc_tconv2<<<STC_ROWS2 / 4, 256, 0, stream>>>(Tch, w2a, b2a, w2b, b2b, w2c, b2c, T2);
    stc_bn<<<STC_N, 256, 0, stream>>>(T2, gam, bet);
}

// Round 7
// 793.527 us; speedup vs baseline: 3.3412x; 3.3412x over previous
//
#include <hip/hip_runtime.h>
#include <hip/hip_bf16.h>

#define STC_N     5000
#define STC_TIN   16
#define STC_T1    14
#define STC_T2    12
#define STC_CIN   16
#define STC_CH    32
#define STC_CO    64
#define STC_BT1   56
#define STC_BT2   48
#define STC_ROWS1 280000
#define STC_ROWS2 240000
#define STC_RT2   15000      /* 240000/16 row-tiles */
#define STC_GBLK  512        /* tconv2 blocks */
#define STC_GWAVE (STC_GBLK*4)

#define STC_OFF_DEG   0
#define STC_OFF_CNT   20000
#define STC_OFF_CUR   40000
#define STC_OFF_DIS   60000
#define STC_OFF_OFFS  80000
#define STC_OFF_WN    100032
#define STC_OFF_CCOL  420032
#define STC_OFF_CW    740032
#define STC_OFF_T0    1060096
#define STC_OFF_G1    (STC_OFF_T0 + 17920000)
#define STC_OFF_G2    (STC_OFF_G1 + 17920000)
#define STC_WS_REQ    (STC_OFF_G2 + 17920000)

typedef __hip_bfloat16 bf16;
typedef short stc_s8 __attribute__((ext_vector_type(8)));
typedef float stc_f4 __attribute__((ext_vector_type(4)));

__device__ float stc_b2f(bf16 v) { return __bfloat162float(v); }

__device__ short stc_f2bs(float f) {          /* f32 -> bf16 bits, RNE */
    unsigned u = __float_as_uint(f);
    u = (u + 0x7FFFu + ((u >> 16) & 1u)) >> 16;
    return (short)u;
}

__global__ void STConv_9972914061616_kernel() {}

__global__ void stc_fill(float* out, int n, float val) {
    int i = blockIdx.x * 256 + threadIdx.x;
    if (i < n) out[i] = val;
}

__global__ void stc_zero(int* p, int n) {
    int i = blockIdx.x * 256 + threadIdx.x;
    if (i < n) p[i] = 0;
}

__global__ void stc_deg(const int* ei, const float* ew, float* deg, int E) {
    int e = blockIdx.x * 256 + threadIdx.x;
    if (e < E) atomicAdd(&deg[ei[e]], ew[e]);
}

__global__ void stc_dis(const float* deg, float* dis, int n) {
    int i = blockIdx.x * 256 + threadIdx.x;
    if (i < n) {
        float d = deg[i];
        dis[i] = (d > 0.0f) ? rsqrtf(d) : 0.0f;
    }
}

__global__ void stc_wnorm(const int* ei, const float* ew, const float* dis,
                          float* wn, int* cnt, int E) {
    int e = blockIdx.x * 256 + threadIdx.x;
    if (e < E) {
        int r = ei[e];
        int c = ei[E + e];
        wn[e] = dis[r] * ew[e] * dis[c];
        atomicAdd(&cnt[r], 1);
    }
}

__global__ void stc_scan(const int* cnt, int* offs, int n) {
    __shared__ int s[256];
    __shared__ int carry;
    if (threadIdx.x == 0) carry = 0;
    __syncthreads();
    for (int base = 0; base < n; base += 256) {
        int i = base + threadIdx.x;
        int v = (i < n) ? cnt[i] : 0;
        s[threadIdx.x] = v;
        __syncthreads();
        for (int off = 1; off < 256; off <<= 1) {
            int t = (threadIdx.x >= off) ? s[threadIdx.x - off] : 0;
            __syncthreads();
            s[threadIdx.x] += t;
            __syncthreads();
        }
        int c0 = carry;
        if (i < n) offs[i] = c0 + s[threadIdx.x] - v;
        __syncthreads();
        if (threadIdx.x == 0) carry = c0 + s[255];
        __syncthreads();
    }
    if (threadIdx.x == 0) offs[n] = carry;
}

__global__ void stc_scatter(const int* ei, const float* wn, const int* offs,
                            int* cursor, int* ccol, float* cw, int E) {
    int e = blockIdx.x * 256 + threadIdx.x;
    if (e < E) {
        int r = ei[e];
        int pos = atomicAdd(&cursor[r], 1);
        int slot = offs[r] + pos;
        ccol[slot] = ei[E + e];
        cw[slot] = wn[e];
    }
}

/* (B,16,N,16)f32 -> (B,14,N,32)bf16: 8 rows x 32 outch per block */
__global__ void stc_tconv1(const float* X,
                           const float* W1, const float* B1,
                           const float* W2, const float* B2,
                           const float* W3, const float* B3,
                           bf16* T0) {
    __shared__ float wl[3][48][32];
    __shared__ float bl[3][32];
    for (int conv = 0; conv < 3; ++conv) {
        const float* Wp = (conv == 0) ? W1 : ((conv == 1) ? W2 : W3);
        for (int i = threadIdx.x; i < 1536; i += 256) {
            int o = i & 31;
            int ck = i >> 5;
            wl[conv][ck][o] = Wp[o * 48 + ck];
        }
    }
    if (threadIdx.x < 96) {
        int conv = threadIdx.x >> 5;
        int o = threadIdx.x & 31;
        const float* Bp = (conv == 0) ? B1 : ((conv == 1) ? B2 : B3);
        bl[conv][o] = Bp[o];
    }
    __syncthreads();

    int r = blockIdx.x * 8 + (threadIdx.x >> 5);
    int o = threadIdx.x & 31;
    if (r >= STC_ROWS1) return;
    int n = r % STC_N;
    int bt = r / STC_N;
    int t = bt % STC_T1;
    int b = bt / STC_T1;

    float P = bl[0][o];
    float Q = bl[1][o];
    float R = bl[2][o];
    for (int k = 0; k < 3; ++k) {
        const float* xp = X + ((size_t)((b * STC_TIN + t + k) * STC_N + n)) * STC_CIN;
        for (int c = 0; c < STC_CIN; ++c) {
            float x = xp[c];
            int ck = c * 3 + k;
            P += x * wl[0][ck][o];
            Q += x * wl[1][ck][o];
            R += x * wl[2][ck][o];
        }
    }
    float Qc = fminf(fmaxf(Q, -30.0f), 30.0f);
    float sg = 1.0f / (1.0f + expf(-Qc));
    float h = P * sg + R;
    if (h < 0.0f) h = 0.0f;
    T0[((size_t)bt * STC_N + n) * STC_CH + o] = __float2bfloat16(h);
}

/* g[bt,n,:] = sum_{e: row==n} w[e] * z[bt,col[e],:]  (z,g: (56,N,32) bf16) */
__global__ void stc_gather(const bf16* z, bf16* g, const int* offs,
                           const int* ccol, const float* cw) {
    int n = blockIdx.x;
    __shared__ int col_s[128];
    __shared__ float w_s[128];
    int beg = offs[n];
    int end = offs[n + 1];
    int p = threadIdx.x >> 5;
    int c = threadIdx.x & 31;
    float a0 = 0.0f, a1 = 0.0f, a2 = 0.0f, a3 = 0.0f, a4 = 0.0f, a5 = 0.0f, a6 = 0.0f;
    for (int chunk = beg; chunk < end; chunk += 128) {
        int m = end - chunk;
        if (m > 128) m = 128;
        if (threadIdx.x < m) {
            col_s[threadIdx.x] = ccol[chunk + threadIdx.x];
            w_s[threadIdx.x] = cw[chunk + threadIdx.x];
        }
        __syncthreads();
        for (int i = 0; i < m; ++i) {
            float w = w_s[i];
            const bf16* zp = z + (size_t)col_s[i] * STC_CH + c;
            size_t st = (size_t)STC_N * STC_CH;
            a0 += w * stc_b2f(zp[(p +  0) * st]);
            a1 += w * stc_b2f(zp[(p +  8) * st]);
            a2 += w * stc_b2f(zp[(p + 16) * st]);
            a3 += w * stc_b2f(zp[(p + 24) * st]);
            a4 += w * stc_b2f(zp[(p + 32) * st]);
            a5 += w * stc_b2f(zp[(p + 40) * st]);
            a6 += w * stc_b2f(zp[(p + 48) * st]);
        }
        __syncthreads();
    }
    size_t go = (size_t)n * STC_CH + c;
    size_t gs = (size_t)STC_N * STC_CH;
    g[go + (p +  0) * gs] = __float2bfloat16(a0);
    g[go + (p +  8) * gs] = __float2bfloat16(a1);
    g[go + (p + 16) * gs] = __float2bfloat16(a2);
    g[go + (p + 24) * gs] = __float2bfloat16(a3);
    g[go + (p + 32) * gs] = __float2bfloat16(a4);
    g[go + (p + 40) * gs] = __float2bfloat16(a5);
    g[go + (p + 48) * gs] = __float2bfloat16(a6);
}

/* Tch = relu(T0*(W0-W2) - G1*W1 + 2*G2*W2 + b); out aliases T0 (per-wave
   read-before-write; rows disjoint across waves; no __restrict__ anywhere) */
__global__ void stc_combine(const bf16* Tx0, const bf16* G1, const bf16* G2,
                            const float* W, const float* bias, bf16* out) {
    __shared__ float wm[3][32][32];
    __shared__ float bl[32];
    for (int i = threadIdx.x; i < 1024; i += 256) {
        float w0 = W[i];
        float w1 = W[1024 + i];
        float w2 = W[2048 + i];
        int c = i >> 5;
        int d = i & 31;
        wm[0][c][d] = w0 - w2;
        wm[1][c][d] = -w1;
        wm[2][c][d] = 2.0f * w2;
    }
    if (threadIdx.x < 32) bl[threadIdx.x] = bias[threadIdx.x];
    __syncthreads();

    int r = blockIdx.x * 8 + (threadIdx.x >> 5);
    int d = threadIdx.x & 31;
    if (r >= STC_ROWS1) return;
    size_t base = (size_t)r * STC_CH;
    float acc = bl[d];
    for (int c = 0; c < STC_CH; ++c) {
        acc += stc_b2f(Tx0[base + c]) * wm[0][c][d];
        acc += stc_b2f(G1[base + c]) * wm[1][c][d];
        acc += stc_b2f(G2[base + c]) * wm[2][c][d];
    }
    if (acc < 0.0f) acc = 0.0f;
    out[base + d] = __float2bfloat16(acc);
}

/* tconv2 as MFMA GEMM: C[240000 x 192] = A[240000 x 96] * B[96 x 192].
   K permuted as k' = kt*32 + c so K-step s == t-plane s and A-frags are
   contiguous 16B bf16 loads. Cols: conv*64 + och (conv 0/1/2 = P/Q/R).
   A-frag (16x16x32): lane holds A[m=lane&15][k = (lane>>4)*8 + i].
   B-frag:            lane holds B[k = (lane>>4)*8 + i][j=lane&15].
   C/D:               lane holds C[row=(lane>>4)*4+reg][col=lane&15]. */
__global__ __launch_bounds__(256, 2) void stc_tconv2m(
    const bf16* Tch,
    const float* W1, const float* B1,
    const float* W2, const float* B2,
    const float* W3, const float* B3,
    float* T2) {
    int lane = threadIdx.x & 63;
    int j = lane & 15;
    int quad = lane >> 4;
    int wave = blockIdx.x * 4 + (threadIdx.x >> 6);

    /* weight B-fragments in registers: [conv][och-tile][kstep] */
    stc_s8 bfrag[3][4][3];
    for (int conv = 0; conv < 3; ++conv) {
        const float* Wp = (conv == 0) ? W1 : ((conv == 1) ? W2 : W3);
        for (int c4 = 0; c4 < 4; ++c4) {
            int och = c4 * 16 + j;
            for (int s = 0; s < 3; ++s) {
                stc_s8 f;
                for (int i = 0; i < 8; ++i) {
                    int cc = quad * 8 + i;
                    f[i] = stc_f2bs(Wp[och * 96 + cc * 3 + s]);
                }
                bfrag[conv][c4][s] = f;
            }
        }
    }
    float pb[4], qb[4], rb[4];
    for (int c4 = 0; c4 < 4; ++c4) {
        int och = c4 * 16 + j;
        pb[c4] = B1[och];
        qb[c4] = B2[och];
        rb[c4] = B3[och];
    }

    for (int rt = wave; rt < STC_RT2; rt += STC_GWAVE) {
        /* A-frag row for this lane */
        int rm = rt * 16 + j;
        int n = rm % STC_N;
        int bt = rm / STC_N;
        int b = bt / STC_T2;
        int t = bt % STC_T2;
        size_t abase = ((size_t)((b * STC_T1 + t) * STC_N + n)) * STC_CH + quad * 8;
        stc_s8 af0 = *(const stc_s8*)(Tch + abase);
        stc_s8 af1 = *(const stc_s8*)(Tch + abase + (size_t)STC_N * STC_CH);
        stc_s8 af2 = *(const stc_s8*)(Tch + abase + (size_t)2 * STC_N * STC_CH);

        stc_f4 acc[12];
        for (int a = 0; a < 12; ++a) acc[a] = (stc_f4){0.0f, 0.0f, 0.0f, 0.0f};

        for (int conv = 0; conv < 3; ++conv) {
            for (int c4 = 0; c4 < 4; ++c4) {
                int a = conv * 4 + c4;
                acc[a] = __builtin_amdgcn_mfma_f32_16x16x32_bf16(
                    af0, bfrag[conv][c4][0], acc[a], 0, 0, 0);
                acc[a] = __builtin_amdgcn_mfma_f32_16x16x32_bf16(
                    af1, bfrag[conv][c4][1], acc[a], 0, 0, 0);
                acc[a] = __builtin_amdgcn_mfma_f32_16x16x32_bf16(
                    af2, bfrag[conv][c4][2], acc[a], 0, 0, 0);
            }
        }

        /* epilogue: P/Q/R for (row, och) live in the same lane */
        for (int c4 = 0; c4 < 4; ++c4) {
            for (int reg = 0; reg < 4; ++reg) {
                float P = acc[c4][reg] + pb[c4];
                float Q = acc[4 + c4][reg] + qb[c4];
                float R = acc[8 + c4][reg] + rb[c4];
                float Qc = fminf(fmaxf(Q, -30.0f), 30.0f);
                float sg = 1.0f / (1.0f + expf(-Qc));
                float h = P * sg + R;
                if (h < 0.0f) h = 0.0f;
                int row = rt * 16 + quad * 4 + reg;
                T2[(size_t)row * STC_CO + c4 * 16 + j] = h;
            }
        }
    }
}

/* per-node batch norm over (B,T,C), in-place on d_out (f32) */
__global__ void stc_bn(float* T2, const float* gamma, const float* beta) {
    int n = blockIdx.x;
    __shared__ float buf[STC_BT2 * STC_CO];
    __shared__ float red[256];
    float s = 0.0f;
    for (int i = threadIdx.x; i < STC_BT2 * STC_CO; i += 256) {
        int p = i >> 6;
        int c = i & 63;
        float v = T2[((size_t)p * STC_N + n) * STC_CO + c];
        buf[i] = v;
        s += v;
    }
    red[threadIdx.x] = s;
    __syncthreads();
    for (int off = 128; off > 0; off >>= 1) {
        if (threadIdx.x < off) red[threadIdx.x] += red[threadIdx.x + off];
        __syncthreads();
    }
    float mean = red[0] * (1.0f / (STC_BT2 * STC_CO));
    __syncthreads();
    float sq = 0.0f;
    for (int i = threadIdx.x; i < STC_BT2 * STC_CO; i += 256) {
        float d = buf[i] - mean;
        sq += d * d;
    }
    red[threadIdx.x] = sq;
    __syncthreads();
    for (int off = 128; off > 0; off >>= 1) {
        if (threadIdx.x < off) red[threadIdx.x] += red[threadIdx.x + off];
        __syncthreads();
    }
    float var = red[0] * (1.0f / (STC_BT2 * STC_CO));
    float istd = rsqrtf(var + 1e-5f);
    float scale = istd * gamma[n];
    float shift = beta[n] - mean * scale;
    for (int i = threadIdx.x; i < STC_BT2 * STC_CO; i += 256) {
        int p = i >> 6;
        int c = i & 63;
        T2[((size_t)p * STC_N + n) * STC_CO + c] = buf[i] * scale + shift;
    }
}

extern "C" void kernel_launch(void* const* d_in, const int* in_sizes, int n_in,
                              void* d_out, int out_size, void* d_ws, size_t ws_size,
                              hipStream_t stream) {
    float* out = (float*)d_out;
    int outb = (out_size + 255) / 256;

    if (n_in < 19) {
        stc_fill<<<outb, 256, 0, stream>>>(out, out_size, 60.0f);
        return;
    }
    if (ws_size < (size_t)STC_WS_REQ) {
        stc_fill<<<outb, 256, 0, stream>>>(out, out_size, 50.0f);
        return;
    }

    const float* X = (const float*)d_in[0];
    const int* ei = (const int*)d_in[1];
    const float* ew = (const float*)d_in[2];
    const float* w1a = (const float*)d_in[3];
    const float* b1a = (const float*)d_in[4];
    const float* w1b = (const float*)d_in[5];
    const float* b1b = (const float*)d_in[6];
    const float* w1c = (const float*)d_in[7];
    const float* b1c = (const float*)d_in[8];
    const float* chW = (const float*)d_in[9];
    const float* chB = (const float*)d_in[10];
    const float* w2a = (const float*)d_in[11];
    const float* b2a = (const float*)d_in[12];
    const float* w2b = (const float*)d_in[13];
    const float* b2b = (const float*)d_in[14];
    const float* w2c = (const float*)d_in[15];
    const float* b2c = (const float*)d_in[16];
    const float* gam = (const float*)d_in[17];
    const float* bet = (const float*)d_in[18];
    int E = in_sizes[1] / 2;

    char* ws = (char*)d_ws;
    float* deg = (float*)(ws + STC_OFF_DEG);
    int* cnt = (int*)(ws + STC_OFF_CNT);
    int* cursor = (int*)(ws + STC_OFF_CUR);
    float* dis = (float*)(ws + STC_OFF_DIS);
    int* offs = (int*)(ws + STC_OFF_OFFS);
    float* wn = (float*)(ws + STC_OFF_WN);
    int* ccol = (int*)(ws + STC_OFF_CCOL);
    float* cw = (float*)(ws + STC_OFF_CW);
    bf16* T0 = (bf16*)(ws + STC_OFF_T0);
    bf16* G1 = (bf16*)(ws + STC_OFF_G1);
    bf16* G2 = (bf16*)(ws + STC_OFF_G2);
    bf16* Tch = T0;          /* alias: per-wave read-before-write safe */
    float* T2 = out;         /* stage tconv2 output in d_out; BN in-place */

    stc_zero<<<59, 256, 0, stream>>>((int*)(ws + STC_OFF_DEG), 15000);
    stc_deg<<<(E + 255) / 256, 256, 0, stream>>>(ei, ew, deg, E);
    stc_dis<<<20, 256, 0, stream>>>(deg, dis, STC_N);
    stc_wnorm<<<(E + 255) / 256, 256, 0, stream>>>(ei, ew, dis, wn, cnt, E);
    stc_scan<<<1, 256, 0, stream>>>(cnt, offs, STC_N);
    stc_scatter<<<(E + 255) / 256, 256, 0, stream>>>(ei, wn, offs, cursor, ccol, cw, E);
    stc_tconv1<<<STC_ROWS1 / 8, 256, 0, stream>>>(X, w1a, b1a, w1b, b1b, w1c, b1c, T0);
    stc_gather<<<STC_N, 256, 0, stream>>>(T0, G1, offs, ccol, cw);
    stc_gather<<<STC_N, 256, 0, stream>>>(G1, G2, offs, ccol, cw);
    stc_combine<<<STC_ROWS1 / 8, 256, 0, stream>>>(T0, G1, G2, chW, chB, Tch);
    stc_tconv2m<<<STC_GBLK, 256, 0, stream>>>(Tch, w2a, b2a, w2b, b2b, w2c, b2c, T2);
    stc_bn<<<STC_N, 256, 0, stream>>>(T2, gam, bet);
}

// Round 8
// 492.469 us; speedup vs baseline: 5.3838x; 1.6113x over previous
//
#include <hip/hip_runtime.h>
#include <hip/hip_bf16.h>

#define STC_N     5000
#define STC_TIN   16
#define STC_T1    14
#define STC_T2    12
#define STC_CIN   16
#define STC_CH    32
#define STC_CO    64
#define STC_BT1   56
#define STC_BT2   48
#define STC_ROWS1 280000
#define STC_ROWS2 240000
#define STC_RT1   17500      /* 280000/16 row-tiles for tconv1 */
#define STC_RT2   15000      /* 240000/16 row-tiles for tconv2 */
#define STC_GBLK  512
#define STC_GWAVE (STC_GBLK*4)

#define STC_OFF_DEG   0
#define STC_OFF_CNT   20000
#define STC_OFF_CUR   40000
#define STC_OFF_DIS   60000
#define STC_OFF_OFFS  80000
#define STC_OFF_WN    100032
#define STC_OFF_CCOL  420032
#define STC_OFF_CW    740032
#define STC_OFF_T0    1060096
#define STC_OFF_G1    (STC_OFF_T0 + 17920000)
#define STC_OFF_G2    (STC_OFF_G1 + 17920000)
#define STC_WS_REQ    (STC_OFF_G2 + 17920000)

typedef __hip_bfloat16 bf16;
typedef short stc_s8 __attribute__((ext_vector_type(8)));
typedef float stc_f4 __attribute__((ext_vector_type(4)));

__device__ float stc_b2f(bf16 v) { return __bfloat162float(v); }

__device__ short stc_f2bs(float f) {          /* f32 -> bf16 bits, RNE */
    unsigned u = __float_as_uint(f);
    u = (u + 0x7FFFu + ((u >> 16) & 1u)) >> 16;
    return (short)u;
}

__global__ void STConv_9972914061616_kernel() {}

__global__ void stc_fill(float* out, int n, float val) {
    int i = blockIdx.x * 256 + threadIdx.x;
    if (i < n) out[i] = val;
}

__global__ void stc_zero(int* p, int n) {
    int i = blockIdx.x * 256 + threadIdx.x;
    if (i < n) p[i] = 0;
}

__global__ void stc_deg(const int* ei, const float* ew, float* deg, int E) {
    int e = blockIdx.x * 256 + threadIdx.x;
    if (e < E) atomicAdd(&deg[ei[e]], ew[e]);
}

__global__ void stc_dis(const float* deg, float* dis, int n) {
    int i = blockIdx.x * 256 + threadIdx.x;
    if (i < n) {
        float d = deg[i];
        dis[i] = (d > 0.0f) ? rsqrtf(d) : 0.0f;
    }
}

__global__ void stc_wnorm(const int* ei, const float* ew, const float* dis,
                          float* wn, int* cnt, int E) {
    int e = blockIdx.x * 256 + threadIdx.x;
    if (e < E) {
        int r = ei[e];
        int c = ei[E + e];
        wn[e] = dis[r] * ew[e] * dis[c];
        atomicAdd(&cnt[r], 1);
    }
}

__global__ void stc_scan(const int* cnt, int* offs, int n) {
    __shared__ int s[256];
    __shared__ int carry;
    if (threadIdx.x == 0) carry = 0;
    __syncthreads();
    for (int base = 0; base < n; base += 256) {
        int i = base + threadIdx.x;
        int v = (i < n) ? cnt[i] : 0;
        s[threadIdx.x] = v;
        __syncthreads();
        for (int off = 1; off < 256; off <<= 1) {
            int t = (threadIdx.x >= off) ? s[threadIdx.x - off] : 0;
            __syncthreads();
            s[threadIdx.x] += t;
            __syncthreads();
        }
        int c0 = carry;
        if (i < n) offs[i] = c0 + s[threadIdx.x] - v;
        __syncthreads();
        if (threadIdx.x == 0) carry = c0 + s[255];
        __syncthreads();
    }
    if (threadIdx.x == 0) offs[n] = carry;
}

__global__ void stc_scatter(const int* ei, const float* wn, const int* offs,
                            int* cursor, int* ccol, float* cw, int E) {
    int e = blockIdx.x * 256 + threadIdx.x;
    if (e < E) {
        int r = ei[e];
        int pos = atomicAdd(&cursor[r], 1);
        int slot = offs[r] + pos;
        ccol[slot] = ei[E + e];
        cw[slot] = wn[e];
    }
}

/* tconv1 as MFMA GEMM: C[280000 x 96] = A[280000 x 48] * B[48 x 96].
   K permuted k' = kt*16 + c. Step0 (k'=0..31) covers t-planes {t,t+1};
   step1 (k'=32..63) covers plane t+2 in quads 0-1, zero-pad in quads 2-3
   (A and B both zero there -> exact). Cols: conv*32 + och. */
__global__ __launch_bounds__(256, 2) void stc_tconv1m(
    const float* X,
    const float* W1, const float* B1,
    const float* W2, const float* B2,
    const float* W3, const float* B3,
    bf16* T0) {
    int lane = threadIdx.x & 63;
    int j = lane & 15;
    int quad = lane >> 4;
    int wave = blockIdx.x * 4 + (threadIdx.x >> 6);

    /* B-frags [conv][och-half][kstep]; W layout o*48 + c*3 + kt */
    stc_s8 bfrag[3][2][2];
    for (int conv = 0; conv < 3; ++conv) {
        const float* Wp = (conv == 0) ? W1 : ((conv == 1) ? W2 : W3);
        for (int jt = 0; jt < 2; ++jt) {
            int och = jt * 16 + j;
            for (int s = 0; s < 2; ++s) {
                stc_s8 f;
                for (int i = 0; i < 8; ++i) {
                    int k = s * 32 + quad * 8 + i;
                    int kt = k >> 4;
                    int c = k & 15;
                    f[i] = (kt < 3) ? stc_f2bs(Wp[och * 48 + c * 3 + kt]) : (short)0;
                }
                bfrag[conv][jt][s] = f;
            }
        }
    }
    float pb[2], qb[2], rb[2];
    for (int jt = 0; jt < 2; ++jt) {
        int och = jt * 16 + j;
        pb[jt] = B1[och];
        qb[jt] = B2[och];
        rb[jt] = B3[och];
    }

    for (int rt = wave; rt < STC_RT1; rt += STC_GWAVE) {
        int rm = rt * 16 + j;
        int n = rm % STC_N;
        int bt = rm / STC_N;
        int t = bt % STC_T1;
        int b = bt / STC_T1;

        /* step0 A-frag: quad0/1 -> plane t, quad2/3 -> plane t+1 */
        int kt0 = quad >> 1;
        int c0 = (quad & 1) * 8;
        const float* xp0 = X + ((size_t)((b * STC_TIN + t + kt0) * STC_N + n)) * STC_CIN + c0;
        stc_s8 af0;
        for (int i = 0; i < 8; ++i) af0[i] = stc_f2bs(xp0[i]);

        /* step1 A-frag: quad0/1 -> plane t+2, quad2/3 -> zero pad */
        stc_s8 af1;
        if (quad < 2) {
            const float* xp1 = X + ((size_t)((b * STC_TIN + t + 2) * STC_N + n)) * STC_CIN + c0;
            for (int i = 0; i < 8; ++i) af1[i] = stc_f2bs(xp1[i]);
        } else {
            for (int i = 0; i < 8; ++i) af1[i] = 0;
        }

        stc_f4 acc[6];
        for (int a = 0; a < 6; ++a) acc[a] = (stc_f4){0.0f, 0.0f, 0.0f, 0.0f};
        for (int conv = 0; conv < 3; ++conv) {
            for (int jt = 0; jt < 2; ++jt) {
                int a = conv * 2 + jt;
                acc[a] = __builtin_amdgcn_mfma_f32_16x16x32_bf16(
                    af0, bfrag[conv][jt][0], acc[a], 0, 0, 0);
                acc[a] = __builtin_amdgcn_mfma_f32_16x16x32_bf16(
                    af1, bfrag[conv][jt][1], acc[a], 0, 0, 0);
            }
        }

        for (int jt = 0; jt < 2; ++jt) {
            for (int reg = 0; reg < 4; ++reg) {
                float P = acc[jt][reg] + pb[jt];
                float Q = acc[2 + jt][reg] + qb[jt];
                float R = acc[4 + jt][reg] + rb[jt];
                float Qc = fminf(fmaxf(Q, -30.0f), 30.0f);
                float sg = 1.0f / (1.0f + expf(-Qc));
                float h = P * sg + R;
                if (h < 0.0f) h = 0.0f;
                int row = rt * 16 + quad * 4 + reg;
                T0[(size_t)row * STC_CH + jt * 16 + j] = __float2bfloat16(h);
            }
        }
    }
}

/* g[bt,n,:] = sum_{e: row==n} w[e] * z[bt,col[e],:]  (z,g: (56,N,32) bf16) */
__global__ void stc_gather(const bf16* z, bf16* g, const int* offs,
                           const int* ccol, const float* cw) {
    int n = blockIdx.x;
    __shared__ int col_s[128];
    __shared__ float w_s[128];
    int beg = offs[n];
    int end = offs[n + 1];
    int p = threadIdx.x >> 5;
    int c = threadIdx.x & 31;
    float a0 = 0.0f, a1 = 0.0f, a2 = 0.0f, a3 = 0.0f, a4 = 0.0f, a5 = 0.0f, a6 = 0.0f;
    for (int chunk = beg; chunk < end; chunk += 128) {
        int m = end - chunk;
        if (m > 128) m = 128;
        if (threadIdx.x < m) {
            col_s[threadIdx.x] = ccol[chunk + threadIdx.x];
            w_s[threadIdx.x] = cw[chunk + threadIdx.x];
        }
        __syncthreads();
        for (int i = 0; i < m; ++i) {
            float w = w_s[i];
            const bf16* zp = z + (size_t)col_s[i] * STC_CH + c;
            size_t st = (size_t)STC_N * STC_CH;
            a0 += w * stc_b2f(zp[(p +  0) * st]);
            a1 += w * stc_b2f(zp[(p +  8) * st]);
            a2 += w * stc_b2f(zp[(p + 16) * st]);
            a3 += w * stc_b2f(zp[(p + 24) * st]);
            a4 += w * stc_b2f(zp[(p + 32) * st]);
            a5 += w * stc_b2f(zp[(p + 40) * st]);
            a6 += w * stc_b2f(zp[(p + 48) * st]);
        }
        __syncthreads();
    }
    size_t go = (size_t)n * STC_CH + c;
    size_t gs = (size_t)STC_N * STC_CH;
    g[go + (p +  0) * gs] = __float2bfloat16(a0);
    g[go + (p +  8) * gs] = __float2bfloat16(a1);
    g[go + (p + 16) * gs] = __float2bfloat16(a2);
    g[go + (p + 24) * gs] = __float2bfloat16(a3);
    g[go + (p + 32) * gs] = __float2bfloat16(a4);
    g[go + (p + 40) * gs] = __float2bfloat16(a5);
    g[go + (p + 48) * gs] = __float2bfloat16(a6);
}

/* Tch = relu(T0*(W0-W2) - G1*W1 + 2*G2*W2 + b); out aliases T0 (per-wave
   read-before-write; rows disjoint across waves; no __restrict__ anywhere) */
__global__ void stc_combine(const bf16* Tx0, const bf16* G1, const bf16* G2,
                            const float* W, const float* bias, bf16* out) {
    __shared__ float wm[3][32][32];
    __shared__ float bl[32];
    for (int i = threadIdx.x; i < 1024; i += 256) {
        float w0 = W[i];
        float w1 = W[1024 + i];
        float w2 = W[2048 + i];
        int c = i >> 5;
        int d = i & 31;
        wm[0][c][d] = w0 - w2;
        wm[1][c][d] = -w1;
        wm[2][c][d] = 2.0f * w2;
    }
    if (threadIdx.x < 32) bl[threadIdx.x] = bias[threadIdx.x];
    __syncthreads();

    int r = blockIdx.x * 8 + (threadIdx.x >> 5);
    int d = threadIdx.x & 31;
    if (r >= STC_ROWS1) return;
    size_t base = (size_t)r * STC_CH;
    float acc = bl[d];
    for (int c = 0; c < STC_CH; ++c) {
        acc += stc_b2f(Tx0[base + c]) * wm[0][c][d];
        acc += stc_b2f(G1[base + c]) * wm[1][c][d];
        acc += stc_b2f(G2[base + c]) * wm[2][c][d];
    }
    if (acc < 0.0f) acc = 0.0f;
    out[base + d] = __float2bfloat16(acc);
}

/* tconv2 as MFMA GEMM: C[240000 x 192] = A[240000 x 96] * B[96 x 192]. */
__global__ __launch_bounds__(256, 2) void stc_tconv2m(
    const bf16* Tch,
    const float* W1, const float* B1,
    const float* W2, const float* B2,
    const float* W3, const float* B3,
    float* T2) {
    int lane = threadIdx.x & 63;
    int j = lane & 15;
    int quad = lane >> 4;
    int wave = blockIdx.x * 4 + (threadIdx.x >> 6);

    stc_s8 bfrag[3][4][3];
    for (int conv = 0; conv < 3; ++conv) {
        const float* Wp = (conv == 0) ? W1 : ((conv == 1) ? W2 : W3);
        for (int c4 = 0; c4 < 4; ++c4) {
            int och = c4 * 16 + j;
            for (int s = 0; s < 3; ++s) {
                stc_s8 f;
                for (int i = 0; i < 8; ++i) {
                    int cc = quad * 8 + i;
                    f[i] = stc_f2bs(Wp[och * 96 + cc * 3 + s]);
                }
                bfrag[conv][c4][s] = f;
            }
        }
    }
    float pb[4], qb[4], rb[4];
    for (int c4 = 0; c4 < 4; ++c4) {
        int och = c4 * 16 + j;
        pb[c4] = B1[och];
        qb[c4] = B2[och];
        rb[c4] = B3[och];
    }

    for (int rt = wave; rt < STC_RT2; rt += STC_GWAVE) {
        int rm = rt * 16 + j;
        int n = rm % STC_N;
        int bt = rm / STC_N;
        int b = bt / STC_T2;
        int t = bt % STC_T2;
        size_t abase = ((size_t)((b * STC_T1 + t) * STC_N + n)) * STC_CH + quad * 8;
        stc_s8 af0 = *(const stc_s8*)(Tch + abase);
        stc_s8 af1 = *(const stc_s8*)(Tch + abase + (size_t)STC_N * STC_CH);
        stc_s8 af2 = *(const stc_s8*)(Tch + abase + (size_t)2 * STC_N * STC_CH);

        stc_f4 acc[12];
        for (int a = 0; a < 12; ++a) acc[a] = (stc_f4){0.0f, 0.0f, 0.0f, 0.0f};

        for (int conv = 0; conv < 3; ++conv) {
            for (int c4 = 0; c4 < 4; ++c4) {
                int a = conv * 4 + c4;
                acc[a] = __builtin_amdgcn_mfma_f32_16x16x32_bf16(
                    af0, bfrag[conv][c4][0], acc[a], 0, 0, 0);
                acc[a] = __builtin_amdgcn_mfma_f32_16x16x32_bf16(
                    af1, bfrag[conv][c4][1], acc[a], 0, 0, 0);
                acc[a] = __builtin_amdgcn_mfma_f32_16x16x32_bf16(
                    af2, bfrag[conv][c4][2], acc[a], 0, 0, 0);
            }
        }

        for (int c4 = 0; c4 < 4; ++c4) {
            for (int reg = 0; reg < 4; ++reg) {
                float P = acc[c4][reg] + pb[c4];
                float Q = acc[4 + c4][reg] + qb[c4];
                float R = acc[8 + c4][reg] + rb[c4];
                float Qc = fminf(fmaxf(Q, -30.0f), 30.0f);
                float sg = 1.0f / (1.0f + expf(-Qc));
                float h = P * sg + R;
                if (h < 0.0f) h = 0.0f;
                int row = rt * 16 + quad * 4 + reg;
                T2[(size_t)row * STC_CO + c4 * 16 + j] = h;
            }
        }
    }
}

/* per-node batch norm over (B,T,C), in-place on d_out (f32) */
__global__ void stc_bn(float* T2, const float* gamma, const float* beta) {
    int n = blockIdx.x;
    __shared__ float buf[STC_BT2 * STC_CO];
    __shared__ float red[256];
    float s = 0.0f;
    for (int i = threadIdx.x; i < STC_BT2 * STC_CO; i += 256) {
        int p = i >> 6;
        int c = i & 63;
        float v = T2[((size_t)p * STC_N + n) * STC_CO + c];
        buf[i] = v;
        s += v;
    }
    red[threadIdx.x] = s;
    __syncthreads();
    for (int off = 128; off > 0; off >>= 1) {
        if (threadIdx.x < off) red[threadIdx.x] += red[threadIdx.x + off];
        __syncthreads();
    }
    float mean = red[0] * (1.0f / (STC_BT2 * STC_CO));
    __syncthreads();
    float sq = 0.0f;
    for (int i = threadIdx.x; i < STC_BT2 * STC_CO; i += 256) {
        float d = buf[i] - mean;
        sq += d * d;
    }
    red[threadIdx.x] = sq;
    __syncthreads();
    for (int off = 128; off > 0; off >>= 1) {
        if (threadIdx.x < off) red[threadIdx.x] += red[threadIdx.x + off];
        __syncthreads();
    }
    float var = red[0] * (1.0f / (STC_BT2 * STC_CO));
    float istd = rsqrtf(var + 1e-5f);
    float scale = istd * gamma[n];
    float shift = beta[n] - mean * scale;
    for (int i = threadIdx.x; i < STC_BT2 * STC_CO; i += 256) {
        int p = i >> 6;
        int c = i & 63;
        T2[((size_t)p * STC_N + n) * STC_CO + c] = buf[i] * scale + shift;
    }
}

extern "C" void kernel_launch(void* const* d_in, const int* in_sizes, int n_in,
                              void* d_out, int out_size, void* d_ws, size_t ws_size,
                              hipStream_t stream) {
    float* out = (float*)d_out;
    int outb = (out_size + 255) / 256;

    if (n_in < 19) {
        stc_fill<<<outb, 256, 0, stream>>>(out, out_size, 60.0f);
        return;
    }
    if (ws_size < (size_t)STC_WS_REQ) {
        stc_fill<<<outb, 256, 0, stream>>>(out, out_size, 50.0f);
        return;
    }

    const float* X = (const float*)d_in[0];
    const int* ei = (const int*)d_in[1];
    const float* ew = (const float*)d_in[2];
    const float* w1a = (const float*)d_in[3];
    const float* b1a = (const float*)d_in[4];
    const float* w1b = (const float*)d_in[5];
    const float* b1b = (const float*)d_in[6];
    const float* w1c = (const float*)d_in[7];
    const float* b1c = (const float*)d_in[8];
    const float* chW = (const float*)d_in[9];
    const float* chB = (const float*)d_in[10];
    const float* w2a = (const float*)d_in[11];
    const float* b2a = (const float*)d_in[12];
    const float* w2b = (const float*)d_in[13];
    const float* b2b = (const float*)d_in[14];
    const float* w2c = (const float*)d_in[15];
    const float* b2c = (const float*)d_in[16];
    const float* gam = (const float*)d_in[17];
    const float* bet = (const float*)d_in[18];
    int E = in_sizes[1] / 2;

    char* ws = (char*)d_ws;
    float* deg = (float*)(ws + STC_OFF_DEG);
    int* cnt = (int*)(ws + STC_OFF_CNT);
    int* cursor = (int*)(ws + STC_OFF_CUR);
    float* dis = (float*)(ws + STC_OFF_DIS);
    int* offs = (int*)(ws + STC_OFF_OFFS);
    float* wn = (float*)(ws + STC_OFF_WN);
    int* ccol = (int*)(ws + STC_OFF_CCOL);
    float* cw = (float*)(ws + STC_OFF_CW);
    bf16* T0 = (bf16*)(ws + STC_OFF_T0);
    bf16* G1 = (bf16*)(ws + STC_OFF_G1);
    bf16* G2 = (bf16*)(ws + STC_OFF_G2);
    bf16* Tch = T0;          /* alias: per-wave read-before-write safe */
    float* T2 = out;         /* stage tconv2 output in d_out; BN in-place */

    stc_zero<<<59, 256, 0, stream>>>((int*)(ws + STC_OFF_DEG), 15000);
    stc_deg<<<(E + 255) / 256, 256, 0, stream>>>(ei, ew, deg, E);
    stc_dis<<<20, 256, 0, stream>>>(deg, dis, STC_N);
    stc_wnorm<<<(E + 255) / 256, 256, 0, stream>>>(ei, ew, dis, wn, cnt, E);
    stc_scan<<<1, 256, 0, stream>>>(cnt, offs, STC_N);
    stc_scatter<<<(E + 255) / 256, 256, 0, stream>>>(ei, wn, offs, cursor, ccol, cw, E);
    stc_tconv1m<<<STC_GBLK, 256, 0, stream>>>(X, w1a, b1a, w1b, b1b, w1c, b1c, T0);
    stc_gather<<<STC_N, 256, 0, stream>>>(T0, G1, offs, ccol, cw);
    stc_gather<<<STC_N, 256, 0, stream>>>(G1, G2, offs, ccol, cw);
    stc_combine<<<STC_ROWS1 / 8, 256, 0, stream>>>(T0, G1, G2, chW, chB, Tch);
    stc_tconv2m<<<STC_GBLK, 256, 0, stream>>>(Tch, w2a, b2a, w2b, b2b, w2c, b2c, T2);
    stc_bn<<<STC_N, 256, 0, stream>>>(T2, gam, bet);
}

// Round 9
// 419.446 us; speedup vs baseline: 6.3210x; 1.1741x over previous
//
#include <hip/hip_runtime.h>
#include <hip/hip_bf16.h>

#define STC_N     5000
#define STC_TIN   16
#define STC_T1    14
#define STC_T2    12
#define STC_CIN   16
#define STC_CH    32
#define STC_CO    64
#define STC_BT1   56
#define STC_BT2   48
#define STC_ROWS1 280000
#define STC_ROWS2 240000
#define STC_RT1   17500      /* 280000/16 row-tiles */
#define STC_RT2   15000      /* 240000/16 row-tiles */
#define STC_GBLK  512
#define STC_GWAVE (STC_GBLK*4)

#define STC_OFF_DEG   0
#define STC_OFF_CNT   20000
#define STC_OFF_CUR   40000
#define STC_OFF_DIS   60000
#define STC_OFF_OFFS  80000
#define STC_OFF_WN    100032
#define STC_OFF_CCOL  420032
#define STC_OFF_CW    740032
#define STC_OFF_T0    1060096
#define STC_OFF_G1    (STC_OFF_T0 + 17920000)
#define STC_OFF_G2    (STC_OFF_G1 + 17920000)
#define STC_WS_REQ    (STC_OFF_G2 + 17920000)

typedef __hip_bfloat16 bf16;
typedef short stc_s8 __attribute__((ext_vector_type(8)));
typedef float stc_f4 __attribute__((ext_vector_type(4)));

__device__ float stc_b2f(bf16 v) { return __bfloat162float(v); }
__device__ float stc_lo16(unsigned u) { return __uint_as_float(u << 16); }
__device__ float stc_hi16(unsigned u) { return __uint_as_float(u & 0xffff0000u); }

__device__ short stc_f2bs(float f) {          /* f32 -> bf16 bits, RNE */
    unsigned u = __float_as_uint(f);
    u = (u + 0x7FFFu + ((u >> 16) & 1u)) >> 16;
    return (short)u;
}

__global__ void STConv_9972914061616_kernel() {}

__global__ void stc_fill(float* out, int n, float val) {
    int i = blockIdx.x * 256 + threadIdx.x;
    if (i < n) out[i] = val;
}

__global__ void stc_zero(int* p, int n) {
    int i = blockIdx.x * 256 + threadIdx.x;
    if (i < n) p[i] = 0;
}

__global__ void stc_deg(const int* ei, const float* ew, float* deg, int E) {
    int e = blockIdx.x * 256 + threadIdx.x;
    if (e < E) atomicAdd(&deg[ei[e]], ew[e]);
}

__global__ void stc_dis(const float* deg, float* dis, int n) {
    int i = blockIdx.x * 256 + threadIdx.x;
    if (i < n) {
        float d = deg[i];
        dis[i] = (d > 0.0f) ? rsqrtf(d) : 0.0f;
    }
}

__global__ void stc_wnorm(const int* ei, const float* ew, const float* dis,
                          float* wn, int* cnt, int E) {
    int e = blockIdx.x * 256 + threadIdx.x;
    if (e < E) {
        int r = ei[e];
        int c = ei[E + e];
        wn[e] = dis[r] * ew[e] * dis[c];
        atomicAdd(&cnt[r], 1);
    }
}

__global__ void stc_scan(const int* cnt, int* offs, int n) {
    __shared__ int s[256];
    __shared__ int carry;
    if (threadIdx.x == 0) carry = 0;
    __syncthreads();
    for (int base = 0; base < n; base += 256) {
        int i = base + threadIdx.x;
        int v = (i < n) ? cnt[i] : 0;
        s[threadIdx.x] = v;
        __syncthreads();
        for (int off = 1; off < 256; off <<= 1) {
            int t = (threadIdx.x >= off) ? s[threadIdx.x - off] : 0;
            __syncthreads();
            s[threadIdx.x] += t;
            __syncthreads();
        }
        int c0 = carry;
        if (i < n) offs[i] = c0 + s[threadIdx.x] - v;
        __syncthreads();
        if (threadIdx.x == 0) carry = c0 + s[255];
        __syncthreads();
    }
    if (threadIdx.x == 0) offs[n] = carry;
}

__global__ void stc_scatter(const int* ei, const float* wn, const int* offs,
                            int* cursor, int* ccol, float* cw, int E) {
    int e = blockIdx.x * 256 + threadIdx.x;
    if (e < E) {
        int r = ei[e];
        int pos = atomicAdd(&cursor[r], 1);
        int slot = offs[r] + pos;
        ccol[slot] = ei[E + e];
        cw[slot] = wn[e];
    }
}

/* tconv1 as MFMA GEMM: C[280000 x 96] = A[280000 x 48] * B[48 x 96]. */
__global__ __launch_bounds__(256, 2) void stc_tconv1m(
    const float* X,
    const float* W1, const float* B1,
    const float* W2, const float* B2,
    const float* W3, const float* B3,
    bf16* T0) {
    int lane = threadIdx.x & 63;
    int j = lane & 15;
    int quad = lane >> 4;
    int wave = blockIdx.x * 4 + (threadIdx.x >> 6);

    stc_s8 bfrag[3][2][2];
    for (int conv = 0; conv < 3; ++conv) {
        const float* Wp = (conv == 0) ? W1 : ((conv == 1) ? W2 : W3);
        for (int jt = 0; jt < 2; ++jt) {
            int och = jt * 16 + j;
            for (int s = 0; s < 2; ++s) {
                stc_s8 f;
                for (int i = 0; i < 8; ++i) {
                    int k = s * 32 + quad * 8 + i;
                    int kt = k >> 4;
                    int c = k & 15;
                    f[i] = (kt < 3) ? stc_f2bs(Wp[och * 48 + c * 3 + kt]) : (short)0;
                }
                bfrag[conv][jt][s] = f;
            }
        }
    }
    float pb[2], qb[2], rb[2];
    for (int jt = 0; jt < 2; ++jt) {
        int och = jt * 16 + j;
        pb[jt] = B1[och];
        qb[jt] = B2[och];
        rb[jt] = B3[och];
    }

    for (int rt = wave; rt < STC_RT1; rt += STC_GWAVE) {
        int rm = rt * 16 + j;
        int n = rm % STC_N;
        int bt = rm / STC_N;
        int t = bt % STC_T1;
        int b = bt / STC_T1;

        int kt0 = quad >> 1;
        int c0 = (quad & 1) * 8;
        const float* xp0 = X + ((size_t)((b * STC_TIN + t + kt0) * STC_N + n)) * STC_CIN + c0;
        stc_s8 af0;
        for (int i = 0; i < 8; ++i) af0[i] = stc_f2bs(xp0[i]);

        stc_s8 af1;
        if (quad < 2) {
            const float* xp1 = X + ((size_t)((b * STC_TIN + t + 2) * STC_N + n)) * STC_CIN + c0;
            for (int i = 0; i < 8; ++i) af1[i] = stc_f2bs(xp1[i]);
        } else {
            for (int i = 0; i < 8; ++i) af1[i] = 0;
        }

        stc_f4 acc[6];
        for (int a = 0; a < 6; ++a) acc[a] = (stc_f4){0.0f, 0.0f, 0.0f, 0.0f};
        for (int conv = 0; conv < 3; ++conv) {
            for (int jt = 0; jt < 2; ++jt) {
                int a = conv * 2 + jt;
                acc[a] = __builtin_amdgcn_mfma_f32_16x16x32_bf16(
                    af0, bfrag[conv][jt][0], acc[a], 0, 0, 0);
                acc[a] = __builtin_amdgcn_mfma_f32_16x16x32_bf16(
                    af1, bfrag[conv][jt][1], acc[a], 0, 0, 0);
            }
        }

        for (int jt = 0; jt < 2; ++jt) {
            for (int reg = 0; reg < 4; ++reg) {
                float P = acc[jt][reg] + pb[jt];
                float Q = acc[2 + jt][reg] + qb[jt];
                float R = acc[4 + jt][reg] + rb[jt];
                float Qc = fminf(fmaxf(Q, -30.0f), 30.0f);
                float sg = 1.0f / (1.0f + expf(-Qc));
                float h = P * sg + R;
                if (h < 0.0f) h = 0.0f;
                int row = rt * 16 + quad * 4 + reg;
                T0[(size_t)row * STC_CH + jt * 16 + j] = __float2bfloat16(h);
            }
        }
    }
}

/* vectorized gather: thread = (bt-slot, 8-ch group); one dwordx4 per edge.
   g[bt,n,:] = sum_{e: row==n} w[e]*z[bt,col[e],:] */
__global__ void stc_gatherv(const bf16* z, bf16* g, const int* offs,
                            const int* ccol, const float* cw) {
    int n = blockIdx.x;
    __shared__ int col_s[128];
    __shared__ float w_s[128];
    int beg = offs[n];
    int end = offs[n + 1];
    int cg = threadIdx.x & 3;        /* 8-channel group 0..3 */
    int sl = threadIdx.x >> 2;       /* bt slot 0..63; active < 56 */
    int act = (sl < STC_BT1);
    float a0 = 0.f, a1 = 0.f, a2 = 0.f, a3 = 0.f;
    float a4 = 0.f, a5 = 0.f, a6 = 0.f, a7 = 0.f;
    const bf16* zb = z + (size_t)sl * STC_N * STC_CH + cg * 8;
    for (int chunk = beg; chunk < end; chunk += 128) {
        int m = end - chunk;
        if (m > 128) m = 128;
        if (threadIdx.x < m) {
            col_s[threadIdx.x] = ccol[chunk + threadIdx.x];
            w_s[threadIdx.x] = cw[chunk + threadIdx.x];
        }
        __syncthreads();
        if (act) {
            for (int i = 0; i < m; ++i) {
                float w = w_s[i];
                uint4 u = *(const uint4*)(zb + (size_t)col_s[i] * STC_CH);
                a0 += w * stc_lo16(u.x);
                a1 += w * stc_hi16(u.x);
                a2 += w * stc_lo16(u.y);
                a3 += w * stc_hi16(u.y);
                a4 += w * stc_lo16(u.z);
                a5 += w * stc_hi16(u.z);
                a6 += w * stc_lo16(u.w);
                a7 += w * stc_hi16(u.w);
            }
        }
        __syncthreads();
    }
    if (act) {
        unsigned p0 = ((unsigned)(unsigned short)stc_f2bs(a0)) |
                      (((unsigned)(unsigned short)stc_f2bs(a1)) << 16);
        unsigned p1 = ((unsigned)(unsigned short)stc_f2bs(a2)) |
                      (((unsigned)(unsigned short)stc_f2bs(a3)) << 16);
        unsigned p2 = ((unsigned)(unsigned short)stc_f2bs(a4)) |
                      (((unsigned)(unsigned short)stc_f2bs(a5)) << 16);
        unsigned p3 = ((unsigned)(unsigned short)stc_f2bs(a6)) |
                      (((unsigned)(unsigned short)stc_f2bs(a7)) << 16);
        uint4 o;
        o.x = p0; o.y = p1; o.z = p2; o.w = p3;
        *(uint4*)(g + ((size_t)sl * STC_N + n) * STC_CH + cg * 8) = o;
    }
}

/* cheb combine as MFMA GEMM: C[280000 x 32] = [T0|G1|G2] * [W0-W2; -W1; 2W2].
   K-step s selects source buffer; out aliases T0 (store data depends on
   same-wave loads of the same rows; tiles are wave-disjoint). */
__global__ __launch_bounds__(256, 2) void stc_combinem(
    const bf16* Tx0, const bf16* G1, const bf16* G2,
    const float* W, const float* bias, bf16* outb) {
    int lane = threadIdx.x & 63;
    int j = lane & 15;
    int quad = lane >> 4;
    int wave = blockIdx.x * 4 + (threadIdx.x >> 6);

    stc_s8 bfrag[3][2];
    for (int s = 0; s < 3; ++s) {
        for (int jt = 0; jt < 2; ++jt) {
            stc_s8 f;
            for (int i = 0; i < 8; ++i) {
                int c = quad * 8 + i;
                int d = jt * 16 + j;
                float w0 = W[c * 32 + d];
                float w1 = W[1024 + c * 32 + d];
                float w2 = W[2048 + c * 32 + d];
                float v = (s == 0) ? (w0 - w2) : ((s == 1) ? -w1 : 2.0f * w2);
                f[i] = stc_f2bs(v);
            }
            bfrag[s][jt] = f;
        }
    }
    float bl[2];
    bl[0] = bias[j];
    bl[1] = bias[16 + j];

    for (int rt = wave; rt < STC_RT1; rt += STC_GWAVE) {
        int rm = rt * 16 + j;
        size_t abase = (size_t)rm * STC_CH + quad * 8;
        stc_s8 a0 = *(const stc_s8*)(Tx0 + abase);
        stc_s8 a1 = *(const stc_s8*)(G1 + abase);
        stc_s8 a2 = *(const stc_s8*)(G2 + abase);

        stc_f4 acc[2];
        acc[0] = (stc_f4){0.0f, 0.0f, 0.0f, 0.0f};
        acc[1] = (stc_f4){0.0f, 0.0f, 0.0f, 0.0f};
        for (int jt = 0; jt < 2; ++jt) {
            acc[jt] = __builtin_amdgcn_mfma_f32_16x16x32_bf16(a0, bfrag[0][jt], acc[jt], 0, 0, 0);
            acc[jt] = __builtin_amdgcn_mfma_f32_16x16x32_bf16(a1, bfrag[1][jt], acc[jt], 0, 0, 0);
            acc[jt] = __builtin_amdgcn_mfma_f32_16x16x32_bf16(a2, bfrag[2][jt], acc[jt], 0, 0, 0);
        }

        for (int jt = 0; jt < 2; ++jt) {
            for (int reg = 0; reg < 4; ++reg) {
                float h = acc[jt][reg] + bl[jt];
                if (h < 0.0f) h = 0.0f;
                int row = rt * 16 + quad * 4 + reg;
                outb[(size_t)row * STC_CH + jt * 16 + j] = __float2bfloat16(h);
            }
        }
    }
}

/* tconv2 as MFMA GEMM: C[240000 x 192] = A[240000 x 96] * B[96 x 192]. */
__global__ __launch_bounds__(256, 2) void stc_tconv2m(
    const bf16* Tch,
    const float* W1, const float* B1,
    const float* W2, const float* B2,
    const float* W3, const float* B3,
    float* T2) {
    int lane = threadIdx.x & 63;
    int j = lane & 15;
    int quad = lane >> 4;
    int wave = blockIdx.x * 4 + (threadIdx.x >> 6);

    stc_s8 bfrag[3][4][3];
    for (int conv = 0; conv < 3; ++conv) {
        const float* Wp = (conv == 0) ? W1 : ((conv == 1) ? W2 : W3);
        for (int c4 = 0; c4 < 4; ++c4) {
            int och = c4 * 16 + j;
            for (int s = 0; s < 3; ++s) {
                stc_s8 f;
                for (int i = 0; i < 8; ++i) {
                    int cc = quad * 8 + i;
                    f[i] = stc_f2bs(Wp[och * 96 + cc * 3 + s]);
                }
                bfrag[conv][c4][s] = f;
            }
        }
    }
    float pb[4], qb[4], rb[4];
    for (int c4 = 0; c4 < 4; ++c4) {
        int och = c4 * 16 + j;
        pb[c4] = B1[och];
        qb[c4] = B2[och];
        rb[c4] = B3[och];
    }

    for (int rt = wave; rt < STC_RT2; rt += STC_GWAVE) {
        int rm = rt * 16 + j;
        int n = rm % STC_N;
        int bt = rm / STC_N;
        int b = bt / STC_T2;
        int t = bt % STC_T2;
        size_t abase = ((size_t)((b * STC_T1 + t) * STC_N + n)) * STC_CH + quad * 8;
        stc_s8 af0 = *(const stc_s8*)(Tch + abase);
        stc_s8 af1 = *(const stc_s8*)(Tch + abase + (size_t)STC_N * STC_CH);
        stc_s8 af2 = *(const stc_s8*)(Tch + abase + (size_t)2 * STC_N * STC_CH);

        stc_f4 acc[12];
        for (int a = 0; a < 12; ++a) acc[a] = (stc_f4){0.0f, 0.0f, 0.0f, 0.0f};

        for (int conv = 0; conv < 3; ++conv) {
            for (int c4 = 0; c4 < 4; ++c4) {
                int a = conv * 4 + c4;
                acc[a] = __builtin_amdgcn_mfma_f32_16x16x32_bf16(
                    af0, bfrag[conv][c4][0], acc[a], 0, 0, 0);
                acc[a] = __builtin_amdgcn_mfma_f32_16x16x32_bf16(
                    af1, bfrag[conv][c4][1], acc[a], 0, 0, 0);
                acc[a] = __builtin_amdgcn_mfma_f32_16x16x32_bf16(
                    af2, bfrag[conv][c4][2], acc[a], 0, 0, 0);
            }
        }

        for (int c4 = 0; c4 < 4; ++c4) {
            for (int reg = 0; reg < 4; ++reg) {
                float P = acc[c4][reg] + pb[c4];
                float Q = acc[4 + c4][reg] + qb[c4];
                float R = acc[8 + c4][reg] + rb[c4];
                float Qc = fminf(fmaxf(Q, -30.0f), 30.0f);
                float sg = 1.0f / (1.0f + expf(-Qc));
                float h = P * sg + R;
                if (h < 0.0f) h = 0.0f;
                int row = rt * 16 + quad * 4 + reg;
                T2[(size_t)row * STC_CO + c4 * 16 + j] = h;
            }
        }
    }
}

/* per-node batch norm over (B,T,C), in-place on d_out (f32) */
__global__ void stc_bn(float* T2, const float* gamma, const float* beta) {
    int n = blockIdx.x;
    __shared__ float buf[STC_BT2 * STC_CO];
    __shared__ float red[256];
    float s = 0.0f;
    for (int i = threadIdx.x; i < STC_BT2 * STC_CO; i += 256) {
        int p = i >> 6;
        int c = i & 63;
        float v = T2[((size_t)p * STC_N + n) * STC_CO + c];
        buf[i] = v;
        s += v;
    }
    red[threadIdx.x] = s;
    __syncthreads();
    for (int off = 128; off > 0; off >>= 1) {
        if (threadIdx.x < off) red[threadIdx.x] += red[threadIdx.x + off];
        __syncthreads();
    }
    float mean = red[0] * (1.0f / (STC_BT2 * STC_CO));
    __syncthreads();
    float sq = 0.0f;
    for (int i = threadIdx.x; i < STC_BT2 * STC_CO; i += 256) {
        float d = buf[i] - mean;
        sq += d * d;
    }
    red[threadIdx.x] = sq;
    __syncthreads();
    for (int off = 128; off > 0; off >>= 1) {
        if (threadIdx.x < off) red[threadIdx.x] += red[threadIdx.x + off];
        __syncthreads();
    }
    float var = red[0] * (1.0f / (STC_BT2 * STC_CO));
    float istd = rsqrtf(var + 1e-5f);
    float scale = istd * gamma[n];
    float shift = beta[n] - mean * scale;
    for (int i = threadIdx.x; i < STC_BT2 * STC_CO; i += 256) {
        int p = i >> 6;
        int c = i & 63;
        T2[((size_t)p * STC_N + n) * STC_CO + c] = buf[i] * scale + shift;
    }
}

extern "C" void kernel_launch(void* const* d_in, const int* in_sizes, int n_in,
                              void* d_out, int out_size, void* d_ws, size_t ws_size,
                              hipStream_t stream) {
    float* out = (float*)d_out;
    int outb = (out_size + 255) / 256;

    if (n_in < 19) {
        stc_fill<<<outb, 256, 0, stream>>>(out, out_size, 60.0f);
        return;
    }
    if (ws_size < (size_t)STC_WS_REQ) {
        stc_fill<<<outb, 256, 0, stream>>>(out, out_size, 50.0f);
        return;
    }

    const float* X = (const float*)d_in[0];
    const int* ei = (const int*)d_in[1];
    const float* ew = (const float*)d_in[2];
    const float* w1a = (const float*)d_in[3];
    const float* b1a = (const float*)d_in[4];
    const float* w1b = (const float*)d_in[5];
    const float* b1b = (const float*)d_in[6];
    const float* w1c = (const float*)d_in[7];
    const float* b1c = (const float*)d_in[8];
    const float* chW = (const float*)d_in[9];
    const float* chB = (const float*)d_in[10];
    const float* w2a = (const float*)d_in[11];
    const float* b2a = (const float*)d_in[12];
    const float* w2b = (const float*)d_in[13];
    const float* b2b = (const float*)d_in[14];
    const float* w2c = (const float*)d_in[15];
    const float* b2c = (const float*)d_in[16];
    const float* gam = (const float*)d_in[17];
    const float* bet = (const float*)d_in[18];
    int E = in_sizes[1] / 2;

    char* ws = (char*)d_ws;
    float* deg = (float*)(ws + STC_OFF_DEG);
    int* cnt = (int*)(ws + STC_OFF_CNT);
    int* cursor = (int*)(ws + STC_OFF_CUR);
    float* dis = (float*)(ws + STC_OFF_DIS);
    int* offs = (int*)(ws + STC_OFF_OFFS);
    float* wn = (float*)(ws + STC_OFF_WN);
    int* ccol = (int*)(ws + STC_OFF_CCOL);
    float* cw = (float*)(ws + STC_OFF_CW);
    bf16* T0 = (bf16*)(ws + STC_OFF_T0);
    bf16* G1 = (bf16*)(ws + STC_OFF_G1);
    bf16* G2 = (bf16*)(ws + STC_OFF_G2);
    bf16* Tch = T0;          /* alias: same-wave read-before-write safe */
    float* T2 = out;         /* stage tconv2 output in d_out; BN in-place */

    stc_zero<<<59, 256, 0, stream>>>((int*)(ws + STC_OFF_DEG), 15000);
    stc_deg<<<(E + 255) / 256, 256, 0, stream>>>(ei, ew, deg, E);
    stc_dis<<<20, 256, 0, stream>>>(deg, dis, STC_N);
    stc_wnorm<<<(E + 255) / 256, 256, 0, stream>>>(ei, ew, dis, wn, cnt, E);
    stc_scan<<<1, 256, 0, stream>>>(cnt, offs, STC_N);
    stc_scatter<<<(E + 255) / 256, 256, 0, stream>>>(ei, wn, offs, cursor, ccol, cw, E);
    stc_tconv1m<<<STC_GBLK, 256, 0, stream>>>(X, w1a, b1a, w1b, b1b, w1c, b1c, T0);
    stc_gatherv<<<STC_N, 256, 0, stream>>>(T0, G1, offs, ccol, cw);
    stc_gatherv<<<STC_N, 256, 0, stream>>>(G1, G2, offs, ccol, cw);
    stc_combinem<<<STC_GBLK, 256, 0, stream>>>(T0, G1, G2, chW, chB, Tch);
    stc_tconv2m<<<STC_GBLK, 256, 0, stream>>>(Tch, w2a, b2a, w2b, b2b, w2c, b2c, T2);
    stc_bn<<<STC_N, 256, 0, stream>>>(T2, gam, bet);
}

// Round 10
// 374.601 us; speedup vs baseline: 7.0778x; 1.1197x over previous
//
#include <hip/hip_runtime.h>
#include <hip/hip_bf16.h>

#define STC_N     5000
#define STC_TIN   16
#define STC_T1    14
#define STC_T2    12
#define STC_CIN   16
#define STC_CH    32
#define STC_CO    64
#define STC_BT1   56
#define STC_BT2   48
#define STC_ROWS1 280000
#define STC_ROWS2 240000
#define STC_RT1   17500      /* 280000/16 row-tiles */
#define STC_RT2   15000      /* 240000/16 row-tiles */
#define STC_GBLK  1280
#define STC_GWAVE (STC_GBLK*4)

#define STC_OFF_DEG   0
#define STC_OFF_CNT   20000
#define STC_OFF_CUR   40000
#define STC_OFF_DIS   60000
#define STC_OFF_OFFS  80000
#define STC_OFF_WN    100032
#define STC_OFF_CCOL  420032
#define STC_OFF_CW    740032
#define STC_OFF_T0    1060096
#define STC_OFF_G1    (STC_OFF_T0 + 17920000)
#define STC_OFF_G2    (STC_OFF_G1 + 17920000)
#define STC_OFF_PK2   (STC_OFF_G2 + 17920000)   /* 36 frags * 512 B */
#define STC_OFF_PK1   (STC_OFF_PK2 + 36864)     /* 12 frags */
#define STC_OFF_PKC   (STC_OFF_PK1 + 12288)     /* 6 frags */
#define STC_WS_REQ    (STC_OFF_PKC + 6144)

typedef __hip_bfloat16 bf16;
typedef short stc_s8 __attribute__((ext_vector_type(8)));
typedef float stc_f4 __attribute__((ext_vector_type(4)));

__device__ float stc_b2f(bf16 v) { return __bfloat162float(v); }
__device__ float stc_lo16(unsigned u) { return __uint_as_float(u << 16); }
__device__ float stc_hi16(unsigned u) { return __uint_as_float(u & 0xffff0000u); }

__device__ short stc_f2bs(float f) {          /* f32 -> bf16 bits, RNE */
    unsigned u = __float_as_uint(f);
    u = (u + 0x7FFFu + ((u >> 16) & 1u)) >> 16;
    return (short)u;
}

__global__ void STConv_9972914061616_kernel() {}

__global__ void stc_fill(float* out, int n, float val) {
    int i = blockIdx.x * 256 + threadIdx.x;
    if (i < n) out[i] = val;
}

__global__ void stc_zero(int* p, int n) {
    int i = blockIdx.x * 256 + threadIdx.x;
    if (i < n) p[i] = 0;
}

__global__ void stc_deg(const int* ei, const float* ew, float* deg, int E) {
    int e = blockIdx.x * 256 + threadIdx.x;
    if (e < E) atomicAdd(&deg[ei[e]], ew[e]);
}

__global__ void stc_dis(const float* deg, float* dis, int n) {
    int i = blockIdx.x * 256 + threadIdx.x;
    if (i < n) {
        float d = deg[i];
        dis[i] = (d > 0.0f) ? rsqrtf(d) : 0.0f;
    }
}

__global__ void stc_wnorm(const int* ei, const float* ew, const float* dis,
                          float* wn, int* cnt, int E) {
    int e = blockIdx.x * 256 + threadIdx.x;
    if (e < E) {
        int r = ei[e];
        int c = ei[E + e];
        wn[e] = dis[r] * ew[e] * dis[c];
        atomicAdd(&cnt[r], 1);
    }
}

__global__ void stc_scan(const int* cnt, int* offs, int n) {
    __shared__ int s[256];
    __shared__ int carry;
    if (threadIdx.x == 0) carry = 0;
    __syncthreads();
    for (int base = 0; base < n; base += 256) {
        int i = base + threadIdx.x;
        int v = (i < n) ? cnt[i] : 0;
        s[threadIdx.x] = v;
        __syncthreads();
        for (int off = 1; off < 256; off <<= 1) {
            int t = (threadIdx.x >= off) ? s[threadIdx.x - off] : 0;
            __syncthreads();
            s[threadIdx.x] += t;
            __syncthreads();
        }
        int c0 = carry;
        if (i < n) offs[i] = c0 + s[threadIdx.x] - v;
        __syncthreads();
        if (threadIdx.x == 0) carry = c0 + s[255];
        __syncthreads();
    }
    if (threadIdx.x == 0) offs[n] = carry;
}

__global__ void stc_scatter(const int* ei, const float* wn, const int* offs,
                            int* cursor, int* ccol, float* cw, int E) {
    int e = blockIdx.x * 256 + threadIdx.x;
    if (e < E) {
        int r = ei[e];
        int pos = atomicAdd(&cursor[r], 1);
        int slot = offs[r] + pos;
        ccol[slot] = ei[E + e];
        cw[slot] = wn[e];
    }
}

/* pack all GEMM weights into MFMA B-frag layout: frag idx * 64 lanes * 8 shorts.
   tconv2: fi 0..35 = (conv*4+c4)*3+s ; tconv1: 36..47 = 36+(conv*2+jt)*2+s ;
   combine: 48..53 = 48 + s*2 + jt. */
__global__ void stc_pack(const float* w1a, const float* w1b, const float* w1c,
                         const float* w2a, const float* w2b, const float* w2c,
                         const float* chW,
                         short* pk1, short* pk2, short* pkc) {
    int gid = blockIdx.x * 256 + threadIdx.x;
    if (gid >= 54 * 64) return;
    int fi = gid >> 6;
    int lane = gid & 63;
    int j = lane & 15;
    int quad = lane >> 4;
    short f[8];
    if (fi < 36) {
        int s = fi % 3;
        int cc4 = fi / 3;
        int conv = cc4 >> 2;
        int c4 = cc4 & 3;
        const float* Wp = (conv == 0) ? w2a : ((conv == 1) ? w2b : w2c);
        int och = c4 * 16 + j;
        for (int i = 0; i < 8; ++i) {
            int cc = quad * 8 + i;
            f[i] = stc_f2bs(Wp[och * 96 + cc * 3 + s]);
        }
        for (int i = 0; i < 8; ++i) pk2[(fi * 64 + lane) * 8 + i] = f[i];
    } else if (fi < 48) {
        int t = fi - 36;
        int s = t & 1;
        int cj = t >> 1;
        int conv = cj >> 1;
        int jt = cj & 1;
        const float* Wp = (conv == 0) ? w1a : ((conv == 1) ? w1b : w1c);
        int och = jt * 16 + j;
        for (int i = 0; i < 8; ++i) {
            int k = s * 32 + quad * 8 + i;
            int kt = k >> 4;
            int c = k & 15;
            f[i] = (kt < 3) ? stc_f2bs(Wp[och * 48 + c * 3 + kt]) : (short)0;
        }
        for (int i = 0; i < 8; ++i) pk1[(t * 64 + lane) * 8 + i] = f[i];
    } else {
        int t = fi - 48;
        int s = t >> 1;
        int jt = t & 1;
        int d = jt * 16 + j;
        for (int i = 0; i < 8; ++i) {
            int c = quad * 8 + i;
            float w0 = chW[c * 32 + d];
            float w1 = chW[1024 + c * 32 + d];
            float w2 = chW[2048 + c * 32 + d];
            float v = (s == 0) ? (w0 - w2) : ((s == 1) ? -w1 : 2.0f * w2);
            f[i] = stc_f2bs(v);
        }
        for (int i = 0; i < 8; ++i) pkc[(t * 64 + lane) * 8 + i] = f[i];
    }
}

/* tconv1 as MFMA GEMM: C[280000 x 96] = A[280000 x 48] * B[48 x 96]. */
__global__ __launch_bounds__(256, 2) void stc_tconv1m(
    const float* X, const short* pk1,
    const float* B1, const float* B2, const float* B3,
    bf16* T0) {
    int lane = threadIdx.x & 63;
    int j = lane & 15;
    int quad = lane >> 4;
    int wave = blockIdx.x * 4 + (threadIdx.x >> 6);

    stc_s8 bfrag[3][2][2];
    for (int conv = 0; conv < 3; ++conv)
        for (int jt = 0; jt < 2; ++jt)
            for (int s = 0; s < 2; ++s) {
                int t = (conv * 2 + jt) * 2 + s;
                bfrag[conv][jt][s] = *(const stc_s8*)(pk1 + (t * 64 + lane) * 8);
            }
    float pb[2], qb[2], rb[2];
    for (int jt = 0; jt < 2; ++jt) {
        int och = jt * 16 + j;
        pb[jt] = B1[och];
        qb[jt] = B2[och];
        rb[jt] = B3[och];
    }

    for (int rt = wave; rt < STC_RT1; rt += STC_GWAVE) {
        int rm = rt * 16 + j;
        int n = rm % STC_N;
        int bt = rm / STC_N;
        int t = bt % STC_T1;
        int b = bt / STC_T1;

        int kt0 = quad >> 1;
        int c0 = (quad & 1) * 8;
        const float* xp0 = X + ((size_t)((b * STC_TIN + t + kt0) * STC_N + n)) * STC_CIN + c0;
        stc_s8 af0;
        for (int i = 0; i < 8; ++i) af0[i] = stc_f2bs(xp0[i]);

        stc_s8 af1;
        if (quad < 2) {
            const float* xp1 = X + ((size_t)((b * STC_TIN + t + 2) * STC_N + n)) * STC_CIN + c0;
            for (int i = 0; i < 8; ++i) af1[i] = stc_f2bs(xp1[i]);
        } else {
            for (int i = 0; i < 8; ++i) af1[i] = 0;
        }

        stc_f4 acc[6];
        for (int a = 0; a < 6; ++a) acc[a] = (stc_f4){0.0f, 0.0f, 0.0f, 0.0f};
        for (int conv = 0; conv < 3; ++conv) {
            for (int jt = 0; jt < 2; ++jt) {
                int a = conv * 2 + jt;
                acc[a] = __builtin_amdgcn_mfma_f32_16x16x32_bf16(
                    af0, bfrag[conv][jt][0], acc[a], 0, 0, 0);
                acc[a] = __builtin_amdgcn_mfma_f32_16x16x32_bf16(
                    af1, bfrag[conv][jt][1], acc[a], 0, 0, 0);
            }
        }

        for (int jt = 0; jt < 2; ++jt) {
            for (int reg = 0; reg < 4; ++reg) {
                float P = acc[jt][reg] + pb[jt];
                float Q = acc[2 + jt][reg] + qb[jt];
                float R = acc[4 + jt][reg] + rb[jt];
                float Qc = fminf(fmaxf(Q, -30.0f), 30.0f);
                float sg = 1.0f / (1.0f + expf(-Qc));
                float h = P * sg + R;
                if (h < 0.0f) h = 0.0f;
                int row = rt * 16 + quad * 4 + reg;
                T0[(size_t)row * STC_CH + jt * 16 + j] = __float2bfloat16(h);
            }
        }
    }
}

/* vectorized gather with 4-way edge unroll for memory-level parallelism */
__global__ void stc_gatherv(const bf16* z, bf16* g, const int* offs,
                            const int* ccol, const float* cw) {
    int n = blockIdx.x;
    __shared__ int col_s[128];
    __shared__ float w_s[128];
    int beg = offs[n];
    int end = offs[n + 1];
    int cg = threadIdx.x & 3;        /* 8-channel group 0..3 */
    int sl = threadIdx.x >> 2;       /* bt slot 0..63; active < 56 */
    int act = (sl < STC_BT1);
    float a0 = 0.f, a1 = 0.f, a2 = 0.f, a3 = 0.f;
    float a4 = 0.f, a5 = 0.f, a6 = 0.f, a7 = 0.f;
    const bf16* zb = z + (size_t)sl * STC_N * STC_CH + cg * 8;
    for (int chunk = beg; chunk < end; chunk += 128) {
        int m = end - chunk;
        if (m > 128) m = 128;
        if (threadIdx.x < m) {
            col_s[threadIdx.x] = ccol[chunk + threadIdx.x];
            w_s[threadIdx.x] = cw[chunk + threadIdx.x];
        }
        __syncthreads();
        if (act) {
            int i = 0;
            for (; i + 4 <= m; i += 4) {
                float w0 = w_s[i], w1 = w_s[i + 1], w2 = w_s[i + 2], w3 = w_s[i + 3];
                uint4 u0 = *(const uint4*)(zb + (size_t)col_s[i] * STC_CH);
                uint4 u1 = *(const uint4*)(zb + (size_t)col_s[i + 1] * STC_CH);
                uint4 u2 = *(const uint4*)(zb + (size_t)col_s[i + 2] * STC_CH);
                uint4 u3 = *(const uint4*)(zb + (size_t)col_s[i + 3] * STC_CH);
                a0 += w0 * stc_lo16(u0.x); a1 += w0 * stc_hi16(u0.x);
                a2 += w0 * stc_lo16(u0.y); a3 += w0 * stc_hi16(u0.y);
                a4 += w0 * stc_lo16(u0.z); a5 += w0 * stc_hi16(u0.z);
                a6 += w0 * stc_lo16(u0.w); a7 += w0 * stc_hi16(u0.w);
                a0 += w1 * stc_lo16(u1.x); a1 += w1 * stc_hi16(u1.x);
                a2 += w1 * stc_lo16(u1.y); a3 += w1 * stc_hi16(u1.y);
                a4 += w1 * stc_lo16(u1.z); a5 += w1 * stc_hi16(u1.z);
                a6 += w1 * stc_lo16(u1.w); a7 += w1 * stc_hi16(u1.w);
                a0 += w2 * stc_lo16(u2.x); a1 += w2 * stc_hi16(u2.x);
                a2 += w2 * stc_lo16(u2.y); a3 += w2 * stc_hi16(u2.y);
                a4 += w2 * stc_lo16(u2.z); a5 += w2 * stc_hi16(u2.z);
                a6 += w2 * stc_lo16(u2.w); a7 += w2 * stc_hi16(u2.w);
                a0 += w3 * stc_lo16(u3.x); a1 += w3 * stc_hi16(u3.x);
                a2 += w3 * stc_lo16(u3.y); a3 += w3 * stc_hi16(u3.y);
                a4 += w3 * stc_lo16(u3.z); a5 += w3 * stc_hi16(u3.z);
                a6 += w3 * stc_lo16(u3.w); a7 += w3 * stc_hi16(u3.w);
            }
            for (; i < m; ++i) {
                float w = w_s[i];
                uint4 u = *(const uint4*)(zb + (size_t)col_s[i] * STC_CH);
                a0 += w * stc_lo16(u.x); a1 += w * stc_hi16(u.x);
                a2 += w * stc_lo16(u.y); a3 += w * stc_hi16(u.y);
                a4 += w * stc_lo16(u.z); a5 += w * stc_hi16(u.z);
                a6 += w * stc_lo16(u.w); a7 += w * stc_hi16(u.w);
            }
        }
        __syncthreads();
    }
    if (act) {
        unsigned p0 = ((unsigned)(unsigned short)stc_f2bs(a0)) |
                      (((unsigned)(unsigned short)stc_f2bs(a1)) << 16);
        unsigned p1 = ((unsigned)(unsigned short)stc_f2bs(a2)) |
                      (((unsigned)(unsigned short)stc_f2bs(a3)) << 16);
        unsigned p2 = ((unsigned)(unsigned short)stc_f2bs(a4)) |
                      (((unsigned)(unsigned short)stc_f2bs(a5)) << 16);
        unsigned p3 = ((unsigned)(unsigned short)stc_f2bs(a6)) |
                      (((unsigned)(unsigned short)stc_f2bs(a7)) << 16);
        uint4 o;
        o.x = p0; o.y = p1; o.z = p2; o.w = p3;
        *(uint4*)(g + ((size_t)sl * STC_N + n) * STC_CH + cg * 8) = o;
    }
}

/* cheb combine as MFMA GEMM; out aliases T0 (same-wave read-before-write) */
__global__ __launch_bounds__(256, 2) void stc_combinem(
    const bf16* Tx0, const bf16* G1, const bf16* G2,
    const short* pkc, const float* bias, bf16* outb) {
    int lane = threadIdx.x & 63;
    int j = lane & 15;
    int quad = lane >> 4;
    int wave = blockIdx.x * 4 + (threadIdx.x >> 6);

    stc_s8 bfrag[3][2];
    for (int s = 0; s < 3; ++s)
        for (int jt = 0; jt < 2; ++jt) {
            int t = s * 2 + jt;
            bfrag[s][jt] = *(const stc_s8*)(pkc + (t * 64 + lane) * 8);
        }
    float bl[2];
    bl[0] = bias[j];
    bl[1] = bias[16 + j];

    for (int rt = wave; rt < STC_RT1; rt += STC_GWAVE) {
        int rm = rt * 16 + j;
        size_t abase = (size_t)rm * STC_CH + quad * 8;
        stc_s8 a0 = *(const stc_s8*)(Tx0 + abase);
        stc_s8 a1 = *(const stc_s8*)(G1 + abase);
        stc_s8 a2 = *(const stc_s8*)(G2 + abase);

        stc_f4 acc[2];
        acc[0] = (stc_f4){0.0f, 0.0f, 0.0f, 0.0f};
        acc[1] = (stc_f4){0.0f, 0.0f, 0.0f, 0.0f};
        for (int jt = 0; jt < 2; ++jt) {
            acc[jt] = __builtin_amdgcn_mfma_f32_16x16x32_bf16(a0, bfrag[0][jt], acc[jt], 0, 0, 0);
            acc[jt] = __builtin_amdgcn_mfma_f32_16x16x32_bf16(a1, bfrag[1][jt], acc[jt], 0, 0, 0);
            acc[jt] = __builtin_amdgcn_mfma_f32_16x16x32_bf16(a2, bfrag[2][jt], acc[jt], 0, 0, 0);
        }

        for (int jt = 0; jt < 2; ++jt) {
            for (int reg = 0; reg < 4; ++reg) {
                float h = acc[jt][reg] + bl[jt];
                if (h < 0.0f) h = 0.0f;
                int row = rt * 16 + quad * 4 + reg;
                outb[(size_t)row * STC_CH + jt * 16 + j] = __float2bfloat16(h);
            }
        }
    }
}

/* tconv2 as MFMA GEMM: C[240000 x 192] = A[240000 x 96] * B[96 x 192]. */
__global__ __launch_bounds__(256, 2) void stc_tconv2m(
    const bf16* Tch, const short* pk2,
    const float* B1, const float* B2, const float* B3,
    float* T2) {
    int lane = threadIdx.x & 63;
    int j = lane & 15;
    int quad = lane >> 4;
    int wave = blockIdx.x * 4 + (threadIdx.x >> 6);

    stc_s8 bfrag[3][4][3];
    for (int conv = 0; conv < 3; ++conv)
        for (int c4 = 0; c4 < 4; ++c4)
            for (int s = 0; s < 3; ++s) {
                int fi = (conv * 4 + c4) * 3 + s;
                bfrag[conv][c4][s] = *(const stc_s8*)(pk2 + (fi * 64 + lane) * 8);
            }
    float pb[4], qb[4], rb[4];
    for (int c4 = 0; c4 < 4; ++c4) {
        int och = c4 * 16 + j;
        pb[c4] = B1[och];
        qb[c4] = B2[och];
        rb[c4] = B3[och];
    }

    for (int rt = wave; rt < STC_RT2; rt += STC_GWAVE) {
        int rm = rt * 16 + j;
        int n = rm % STC_N;
        int bt = rm / STC_N;
        int b = bt / STC_T2;
        int t = bt % STC_T2;
        size_t abase = ((size_t)((b * STC_T1 + t) * STC_N + n)) * STC_CH + quad * 8;
        stc_s8 af0 = *(const stc_s8*)(Tch + abase);
        stc_s8 af1 = *(const stc_s8*)(Tch + abase + (size_t)STC_N * STC_CH);
        stc_s8 af2 = *(const stc_s8*)(Tch + abase + (size_t)2 * STC_N * STC_CH);

        stc_f4 acc[12];
        for (int a = 0; a < 12; ++a) acc[a] = (stc_f4){0.0f, 0.0f, 0.0f, 0.0f};

        for (int conv = 0; conv < 3; ++conv) {
            for (int c4 = 0; c4 < 4; ++c4) {
                int a = conv * 4 + c4;
                acc[a] = __builtin_amdgcn_mfma_f32_16x16x32_bf16(
                    af0, bfrag[conv][c4][0], acc[a], 0, 0, 0);
                acc[a] = __builtin_amdgcn_mfma_f32_16x16x32_bf16(
                    af1, bfrag[conv][c4][1], acc[a], 0, 0, 0);
                acc[a] = __builtin_amdgcn_mfma_f32_16x16x32_bf16(
                    af2, bfrag[conv][c4][2], acc[a], 0, 0, 0);
            }
        }

        for (int c4 = 0; c4 < 4; ++c4) {
            for (int reg = 0; reg < 4; ++reg) {
                float P = acc[c4][reg] + pb[c4];
                float Q = acc[4 + c4][reg] + qb[c4];
                float R = acc[8 + c4][reg] + rb[c4];
                float Qc = fminf(fmaxf(Q, -30.0f), 30.0f);
                float sg = 1.0f / (1.0f + expf(-Qc));
                float h = P * sg + R;
                if (h < 0.0f) h = 0.0f;
                int row = rt * 16 + quad * 4 + reg;
                T2[(size_t)row * STC_CO + c4 * 16 + j] = h;
            }
        }
    }
}

/* per-node batch norm over (B,T,C), in-place on d_out (f32) */
__global__ void stc_bn(float* T2, const float* gamma, const float* beta) {
    int n = blockIdx.x;
    __shared__ float buf[STC_BT2 * STC_CO];
    __shared__ float red[256];
    float s = 0.0f;
    for (int i = threadIdx.x; i < STC_BT2 * STC_CO; i += 256) {
        int p = i >> 6;
        int c = i & 63;
        float v = T2[((size_t)p * STC_N + n) * STC_CO + c];
        buf[i] = v;
        s += v;
    }
    red[threadIdx.x] = s;
    __syncthreads();
    for (int off = 128; off > 0; off >>= 1) {
        if (threadIdx.x < off) red[threadIdx.x] += red[threadIdx.x + off];
        __syncthreads();
    }
    float mean = red[0] * (1.0f / (STC_BT2 * STC_CO));
    __syncthreads();
    float sq = 0.0f;
    for (int i = threadIdx.x; i < STC_BT2 * STC_CO; i += 256) {
        float d = buf[i] - mean;
        sq += d * d;
    }
    red[threadIdx.x] = sq;
    __syncthreads();
    for (int off = 128; off > 0; off >>= 1) {
        if (threadIdx.x < off) red[threadIdx.x] += red[threadIdx.x + off];
        __syncthreads();
    }
    float var = red[0] * (1.0f / (STC_BT2 * STC_CO));
    float istd = rsqrtf(var + 1e-5f);
    float scale = istd * gamma[n];
    float shift = beta[n] - mean * scale;
    for (int i = threadIdx.x; i < STC_BT2 * STC_CO; i += 256) {
        int p = i >> 6;
        int c = i & 63;
        T2[((size_t)p * STC_N + n) * STC_CO + c] = buf[i] * scale + shift;
    }
}

extern "C" void kernel_launch(void* const* d_in, const int* in_sizes, int n_in,
                              void* d_out, int out_size, void* d_ws, size_t ws_size,
                              hipStream_t stream) {
    float* out = (float*)d_out;
    int outb = (out_size + 255) / 256;

    if (n_in < 19) {
        stc_fill<<<outb, 256, 0, stream>>>(out, out_size, 60.0f);
        return;
    }
    if (ws_size < (size_t)STC_WS_REQ) {
        stc_fill<<<outb, 256, 0, stream>>>(out, out_size, 50.0f);
        return;
    }

    const float* X = (const float*)d_in[0];
    const int* ei = (const int*)d_in[1];
    const float* ew = (const float*)d_in[2];
    const float* w1a = (const float*)d_in[3];
    const float* b1a = (const float*)d_in[4];
    const float* w1b = (const float*)d_in[5];
    const float* b1b = (const float*)d_in[6];
    const float* w1c = (const float*)d_in[7];
    const float* b1c = (const float*)d_in[8];
    const float* chW = (const float*)d_in[9];
    const float* chB = (const float*)d_in[10];
    const float* w2a = (const float*)d_in[11];
    const float* b2a = (const float*)d_in[12];
    const float* w2b = (const float*)d_in[13];
    const float* b2b = (const float*)d_in[14];
    const float* w2c = (const float*)d_in[15];
    const float* b2c = (const float*)d_in[16];
    const float* gam = (const float*)d_in[17];
    const float* bet = (const float*)d_in[18];
    int E = in_sizes[1] / 2;

    char* ws = (char*)d_ws;
    float* deg = (float*)(ws + STC_OFF_DEG);
    int* cnt = (int*)(ws + STC_OFF_CNT);
    int* cursor = (int*)(ws + STC_OFF_CUR);
    float* dis = (float*)(ws + STC_OFF_DIS);
    int* offs = (int*)(ws + STC_OFF_OFFS);
    float* wn = (float*)(ws + STC_OFF_WN);
    int* ccol = (int*)(ws + STC_OFF_CCOL);
    float* cw = (float*)(ws + STC_OFF_CW);
    bf16* T0 = (bf16*)(ws + STC_OFF_T0);
    bf16* G1 = (bf16*)(ws + STC_OFF_G1);
    bf16* G2 = (bf16*)(ws + STC_OFF_G2);
    short* pk2 = (short*)(ws + STC_OFF_PK2);
    short* pk1 = (short*)(ws + STC_OFF_PK1);
    short* pkc = (short*)(ws + STC_OFF_PKC);
    bf16* Tch = T0;          /* alias: same-wave read-before-write safe */
    float* T2 = out;         /* stage tconv2 output in d_out; BN in-place */

    stc_zero<<<59, 256, 0, stream>>>((int*)(ws + STC_OFF_DEG), 15000);
    stc_pack<<<14, 256, 0, stream>>>(w1a, w1b, w1c, w2a, w2b, w2c, chW, pk1, pk2, pkc);
    stc_deg<<<(E + 255) / 256, 256, 0, stream>>>(ei, ew, deg, E);
    stc_dis<<<20, 256, 0, stream>>>(deg, dis, STC_N);
    stc_wnorm<<<(E + 255) / 256, 256, 0, stream>>>(ei, ew, dis, wn, cnt, E);
    stc_scan<<<1, 256, 0, stream>>>(cnt, offs, STC_N);
    stc_scatter<<<(E + 255) / 256, 256, 0, stream>>>(ei, wn, offs, cursor, ccol, cw, E);
    stc_tconv1m<<<STC_GBLK, 256, 0, stream>>>(X, pk1, b1a, b1b, b1c, T0);
    stc_gatherv<<<STC_N, 256, 0, stream>>>(T0, G1, offs, ccol, cw);
    stc_gatherv<<<STC_N, 256, 0, stream>>>(G1, G2, offs, ccol, cw);
    stc_combinem<<<STC_GBLK, 256, 0, stream>>>(T0, G1, G2, pkc, chB, Tch);
    stc_tconv2m<<<STC_GBLK, 256, 0, stream>>>(Tch, pk2, b2a, b2b, b2c, T2);
    stc_bn<<<STC_N, 256, 0, stream>>>(T2, gam, bet);
}

// Round 11
// 315.422 us; speedup vs baseline: 8.4057x; 1.1876x over previous
//
#include <hip/hip_runtime.h>
#include <hip/hip_bf16.h>

#define STC_N     5000
#define STC_TIN   16
#define STC_T1    14
#define STC_T2    12
#define STC_CIN   16
#define STC_CH    32
#define STC_CO    64
#define STC_BT1   56
#define STC_BT2   48
#define STC_ROWS1 280000
#define STC_ROWS2 240000
#define STC_RT1   17500      /* 280000/16 row-tiles */
#define STC_RT2   15000      /* 240000/16 row-tiles */
#define STC_GBLK  1280
#define STC_GWAVE (STC_GBLK*4)
#define STC_ROWB1 1792       /* BT1*CH elements per node (transposed layout) */

#define STC_OFF_DEG   0
#define STC_OFF_CNT   20000
#define STC_OFF_CUR   40000
#define STC_OFF_DIS   60000
#define STC_OFF_OFFS  80000
#define STC_OFF_WN    100032
#define STC_OFF_CCOL  420032
#define STC_OFF_CW    740032
#define STC_OFF_T0    1060096
#define STC_OFF_G1    (STC_OFF_T0 + 17920000)
#define STC_OFF_G2    (STC_OFF_G1 + 17920000)
#define STC_OFF_PK2   (STC_OFF_G2 + 17920000)   /* 36 frags * 512 B */
#define STC_OFF_PK1   (STC_OFF_PK2 + 36864)     /* 12 frags */
#define STC_OFF_PKC   (STC_OFF_PK1 + 12288)     /* 6 frags */
#define STC_WS_REQ    (STC_OFF_PKC + 6144)

typedef __hip_bfloat16 bf16;
typedef short stc_s8 __attribute__((ext_vector_type(8)));
typedef float stc_f4 __attribute__((ext_vector_type(4)));

__device__ float stc_b2f(bf16 v) { return __bfloat162float(v); }
__device__ float stc_lo16(unsigned u) { return __uint_as_float(u << 16); }
__device__ float stc_hi16(unsigned u) { return __uint_as_float(u & 0xffff0000u); }

__device__ short stc_f2bs(float f) {          /* f32 -> bf16 bits, RNE */
    unsigned u = __float_as_uint(f);
    u = (u + 0x7FFFu + ((u >> 16) & 1u)) >> 16;
    return (short)u;
}

__global__ void STConv_9972914061616_kernel() {}

__global__ void stc_fill(float* out, int n, float val) {
    int i = blockIdx.x * 256 + threadIdx.x;
    if (i < n) out[i] = val;
}

__global__ void stc_zero(int* p, int n) {
    int i = blockIdx.x * 256 + threadIdx.x;
    if (i < n) p[i] = 0;
}

__global__ void stc_deg(const int* ei, const float* ew, float* deg, int E) {
    int e = blockIdx.x * 256 + threadIdx.x;
    if (e < E) atomicAdd(&deg[ei[e]], ew[e]);
}

__global__ void stc_dis(const float* deg, float* dis, int n) {
    int i = blockIdx.x * 256 + threadIdx.x;
    if (i < n) {
        float d = deg[i];
        dis[i] = (d > 0.0f) ? rsqrtf(d) : 0.0f;
    }
}

__global__ void stc_wnorm(const int* ei, const float* ew, const float* dis,
                          float* wn, int* cnt, int E) {
    int e = blockIdx.x * 256 + threadIdx.x;
    if (e < E) {
        int r = ei[e];
        int c = ei[E + e];
        wn[e] = dis[r] * ew[e] * dis[c];
        atomicAdd(&cnt[r], 1);
    }
}

__global__ void stc_scan(const int* cnt, int* offs, int n) {
    __shared__ int s[256];
    __shared__ int carry;
    if (threadIdx.x == 0) carry = 0;
    __syncthreads();
    for (int base = 0; base < n; base += 256) {
        int i = base + threadIdx.x;
        int v = (i < n) ? cnt[i] : 0;
        s[threadIdx.x] = v;
        __syncthreads();
        for (int off = 1; off < 256; off <<= 1) {
            int t = (threadIdx.x >= off) ? s[threadIdx.x - off] : 0;
            __syncthreads();
            s[threadIdx.x] += t;
            __syncthreads();
        }
        int c0 = carry;
        if (i < n) offs[i] = c0 + s[threadIdx.x] - v;
        __syncthreads();
        if (threadIdx.x == 0) carry = c0 + s[255];
        __syncthreads();
    }
    if (threadIdx.x == 0) offs[n] = carry;
}

__global__ void stc_scatter(const int* ei, const float* wn, const int* offs,
                            int* cursor, int* ccol, float* cw, int E) {
    int e = blockIdx.x * 256 + threadIdx.x;
    if (e < E) {
        int r = ei[e];
        int pos = atomicAdd(&cursor[r], 1);
        int slot = offs[r] + pos;
        ccol[slot] = ei[E + e];
        cw[slot] = wn[e];
    }
}

/* pack all GEMM weights into MFMA B-frag layout: frag idx * 64 lanes * 8 shorts. */
__global__ void stc_pack(const float* w1a, const float* w1b, const float* w1c,
                         const float* w2a, const float* w2b, const float* w2c,
                         const float* chW,
                         short* pk1, short* pk2, short* pkc) {
    int gid = blockIdx.x * 256 + threadIdx.x;
    if (gid >= 54 * 64) return;
    int fi = gid >> 6;
    int lane = gid & 63;
    int j = lane & 15;
    int quad = lane >> 4;
    short f[8];
    if (fi < 36) {
        int s = fi % 3;
        int cc4 = fi / 3;
        int conv = cc4 >> 2;
        int c4 = cc4 & 3;
        const float* Wp = (conv == 0) ? w2a : ((conv == 1) ? w2b : w2c);
        int och = c4 * 16 + j;
        for (int i = 0; i < 8; ++i) {
            int cc = quad * 8 + i;
            f[i] = stc_f2bs(Wp[och * 96 + cc * 3 + s]);
        }
        for (int i = 0; i < 8; ++i) pk2[(fi * 64 + lane) * 8 + i] = f[i];
    } else if (fi < 48) {
        int t = fi - 36;
        int s = t & 1;
        int cj = t >> 1;
        int conv = cj >> 1;
        int jt = cj & 1;
        const float* Wp = (conv == 0) ? w1a : ((conv == 1) ? w1b : w1c);
        int och = jt * 16 + j;
        for (int i = 0; i < 8; ++i) {
            int k = s * 32 + quad * 8 + i;
            int kt = k >> 4;
            int c = k & 15;
            f[i] = (kt < 3) ? stc_f2bs(Wp[och * 48 + c * 3 + kt]) : (short)0;
        }
        for (int i = 0; i < 8; ++i) pk1[(t * 64 + lane) * 8 + i] = f[i];
    } else {
        int t = fi - 48;
        int s = t >> 1;
        int jt = t & 1;
        int d = jt * 16 + j;
        for (int i = 0; i < 8; ++i) {
            int c = quad * 8 + i;
            float w0 = chW[c * 32 + d];
            float w1 = chW[1024 + c * 32 + d];
            float w2 = chW[2048 + c * 32 + d];
            float v = (s == 0) ? (w0 - w2) : ((s == 1) ? -w1 : 2.0f * w2);
            f[i] = stc_f2bs(v);
        }
        for (int i = 0; i < 8; ++i) pkc[(t * 64 + lane) * 8 + i] = f[i];
    }
}

/* tconv1 as MFMA GEMM: C[280000 x 96] = A[280000 x 48] * B[48 x 96].
   GEMM rows enumerated bt*N+n (coalesced X reads); OUTPUT written in
   transposed node-major layout T0[n*56*32 + bt*32 + och]. */
__global__ __launch_bounds__(256, 2) void stc_tconv1m(
    const float* X, const short* pk1,
    const float* B1, const float* B2, const float* B3,
    bf16* T0) {
    int lane = threadIdx.x & 63;
    int j = lane & 15;
    int quad = lane >> 4;
    int wave = blockIdx.x * 4 + (threadIdx.x >> 6);

    stc_s8 bfrag[3][2][2];
    for (int conv = 0; conv < 3; ++conv)
        for (int jt = 0; jt < 2; ++jt)
            for (int s = 0; s < 2; ++s) {
                int t = (conv * 2 + jt) * 2 + s;
                bfrag[conv][jt][s] = *(const stc_s8*)(pk1 + (t * 64 + lane) * 8);
            }
    float pb[2], qb[2], rb[2];
    for (int jt = 0; jt < 2; ++jt) {
        int och = jt * 16 + j;
        pb[jt] = B1[och];
        qb[jt] = B2[och];
        rb[jt] = B3[och];
    }

    for (int rt = wave; rt < STC_RT1; rt += STC_GWAVE) {
        int rm = rt * 16 + j;
        int n = rm % STC_N;
        int bt = rm / STC_N;
        int t = bt % STC_T1;
        int b = bt / STC_T1;

        int kt0 = quad >> 1;
        int c0 = (quad & 1) * 8;
        const float* xp0 = X + ((size_t)((b * STC_TIN + t + kt0) * STC_N + n)) * STC_CIN + c0;
        stc_s8 af0;
        for (int i = 0; i < 8; ++i) af0[i] = stc_f2bs(xp0[i]);

        stc_s8 af1;
        if (quad < 2) {
            const float* xp1 = X + ((size_t)((b * STC_TIN + t + 2) * STC_N + n)) * STC_CIN + c0;
            for (int i = 0; i < 8; ++i) af1[i] = stc_f2bs(xp1[i]);
        } else {
            for (int i = 0; i < 8; ++i) af1[i] = 0;
        }

        stc_f4 acc[6];
        for (int a = 0; a < 6; ++a) acc[a] = (stc_f4){0.0f, 0.0f, 0.0f, 0.0f};
        for (int conv = 0; conv < 3; ++conv) {
            for (int jt = 0; jt < 2; ++jt) {
                int a = conv * 2 + jt;
                acc[a] = __builtin_amdgcn_mfma_f32_16x16x32_bf16(
                    af0, bfrag[conv][jt][0], acc[a], 0, 0, 0);
                acc[a] = __builtin_amdgcn_mfma_f32_16x16x32_bf16(
                    af1, bfrag[conv][jt][1], acc[a], 0, 0, 0);
            }
        }

        for (int jt = 0; jt < 2; ++jt) {
            for (int reg = 0; reg < 4; ++reg) {
                float P = acc[jt][reg] + pb[jt];
                float Q = acc[2 + jt][reg] + qb[jt];
                float R = acc[4 + jt][reg] + rb[jt];
                float Qc = fminf(fmaxf(Q, -30.0f), 30.0f);
                float sg = 1.0f / (1.0f + expf(-Qc));
                float h = P * sg + R;
                if (h < 0.0f) h = 0.0f;
                int row = rt * 16 + quad * 4 + reg;
                int nw = row % STC_N;
                int btw = row / STC_N;
                T0[(size_t)nw * STC_ROWB1 + btw * STC_CH + jt * 16 + j] =
                    __float2bfloat16(h);
            }
        }
    }
}

/* gather on transposed layout: each edge's payload is 3584 contiguous B.
   thread (sl,cg): sl = bt slot, cg = 8-ch group; wave reads 1 KB bursts. */
__global__ void stc_gatherv(const bf16* z, bf16* g, const int* offs,
                            const int* ccol, const float* cw) {
    int n = blockIdx.x;
    __shared__ int col_s[128];
    __shared__ float w_s[128];
    int beg = offs[n];
    int end = offs[n + 1];
    int cg = threadIdx.x & 3;
    int sl = threadIdx.x >> 2;
    int act = (sl < STC_BT1);
    float a0 = 0.f, a1 = 0.f, a2 = 0.f, a3 = 0.f;
    float a4 = 0.f, a5 = 0.f, a6 = 0.f, a7 = 0.f;
    const bf16* zb = z + sl * STC_CH + cg * 8;
    for (int chunk = beg; chunk < end; chunk += 128) {
        int m = end - chunk;
        if (m > 128) m = 128;
        if (threadIdx.x < m) {
            col_s[threadIdx.x] = ccol[chunk + threadIdx.x];
            w_s[threadIdx.x] = cw[chunk + threadIdx.x];
        }
        __syncthreads();
        if (act) {
            int i = 0;
            for (; i + 4 <= m; i += 4) {
                float w0 = w_s[i], w1 = w_s[i + 1], w2 = w_s[i + 2], w3 = w_s[i + 3];
                uint4 u0 = *(const uint4*)(zb + (size_t)col_s[i] * STC_ROWB1);
                uint4 u1 = *(const uint4*)(zb + (size_t)col_s[i + 1] * STC_ROWB1);
                uint4 u2 = *(const uint4*)(zb + (size_t)col_s[i + 2] * STC_ROWB1);
                uint4 u3 = *(const uint4*)(zb + (size_t)col_s[i + 3] * STC_ROWB1);
                a0 += w0 * stc_lo16(u0.x); a1 += w0 * stc_hi16(u0.x);
                a2 += w0 * stc_lo16(u0.y); a3 += w0 * stc_hi16(u0.y);
                a4 += w0 * stc_lo16(u0.z); a5 += w0 * stc_hi16(u0.z);
                a6 += w0 * stc_lo16(u0.w); a7 += w0 * stc_hi16(u0.w);
                a0 += w1 * stc_lo16(u1.x); a1 += w1 * stc_hi16(u1.x);
                a2 += w1 * stc_lo16(u1.y); a3 += w1 * stc_hi16(u1.y);
                a4 += w1 * stc_lo16(u1.z); a5 += w1 * stc_hi16(u1.z);
                a6 += w1 * stc_lo16(u1.w); a7 += w1 * stc_hi16(u1.w);
                a0 += w2 * stc_lo16(u2.x); a1 += w2 * stc_hi16(u2.x);
                a2 += w2 * stc_lo16(u2.y); a3 += w2 * stc_hi16(u2.y);
                a4 += w2 * stc_lo16(u2.z); a5 += w2 * stc_hi16(u2.z);
                a6 += w2 * stc_lo16(u2.w); a7 += w2 * stc_hi16(u2.w);
                a0 += w3 * stc_lo16(u3.x); a1 += w3 * stc_hi16(u3.x);
                a2 += w3 * stc_lo16(u3.y); a3 += w3 * stc_hi16(u3.y);
                a4 += w3 * stc_lo16(u3.z); a5 += w3 * stc_hi16(u3.z);
                a6 += w3 * stc_lo16(u3.w); a7 += w3 * stc_hi16(u3.w);
            }
            for (; i < m; ++i) {
                float w = w_s[i];
                uint4 u = *(const uint4*)(zb + (size_t)col_s[i] * STC_ROWB1);
                a0 += w * stc_lo16(u.x); a1 += w * stc_hi16(u.x);
                a2 += w * stc_lo16(u.y); a3 += w * stc_hi16(u.y);
                a4 += w * stc_lo16(u.z); a5 += w * stc_hi16(u.z);
                a6 += w * stc_lo16(u.w); a7 += w * stc_hi16(u.w);
            }
        }
        __syncthreads();
    }
    if (act) {
        unsigned p0 = ((unsigned)(unsigned short)stc_f2bs(a0)) |
                      (((unsigned)(unsigned short)stc_f2bs(a1)) << 16);
        unsigned p1 = ((unsigned)(unsigned short)stc_f2bs(a2)) |
                      (((unsigned)(unsigned short)stc_f2bs(a3)) << 16);
        unsigned p2 = ((unsigned)(unsigned short)stc_f2bs(a4)) |
                      (((unsigned)(unsigned short)stc_f2bs(a5)) << 16);
        unsigned p3 = ((unsigned)(unsigned short)stc_f2bs(a6)) |
                      (((unsigned)(unsigned short)stc_f2bs(a7)) << 16);
        uint4 o;
        o.x = p0; o.y = p1; o.z = p2; o.w = p3;
        *(uint4*)(g + (size_t)n * STC_ROWB1 + sl * STC_CH + cg * 8) = o;
    }
}

/* cheb combine as MFMA GEMM on transposed layout: pure row permutation,
   linear addressing r'*32 identical; out aliases T0 (same-wave RAW safe) */
__global__ __launch_bounds__(256, 2) void stc_combinem(
    const bf16* Tx0, const bf16* G1, const bf16* G2,
    const short* pkc, const float* bias, bf16* outb) {
    int lane = threadIdx.x & 63;
    int j = lane & 15;
    int quad = lane >> 4;
    int wave = blockIdx.x * 4 + (threadIdx.x >> 6);

    stc_s8 bfrag[3][2];
    for (int s = 0; s < 3; ++s)
        for (int jt = 0; jt < 2; ++jt) {
            int t = s * 2 + jt;
            bfrag[s][jt] = *(const stc_s8*)(pkc + (t * 64 + lane) * 8);
        }
    float bl[2];
    bl[0] = bias[j];
    bl[1] = bias[16 + j];

    for (int rt = wave; rt < STC_RT1; rt += STC_GWAVE) {
        int rm = rt * 16 + j;
        size_t abase = (size_t)rm * STC_CH + quad * 8;
        stc_s8 a0 = *(const stc_s8*)(Tx0 + abase);
        stc_s8 a1 = *(const stc_s8*)(G1 + abase);
        stc_s8 a2 = *(const stc_s8*)(G2 + abase);

        stc_f4 acc[2];
        acc[0] = (stc_f4){0.0f, 0.0f, 0.0f, 0.0f};
        acc[1] = (stc_f4){0.0f, 0.0f, 0.0f, 0.0f};
        for (int jt = 0; jt < 2; ++jt) {
            acc[jt] = __builtin_amdgcn_mfma_f32_16x16x32_bf16(a0, bfrag[0][jt], acc[jt], 0, 0, 0);
            acc[jt] = __builtin_amdgcn_mfma_f32_16x16x32_bf16(a1, bfrag[1][jt], acc[jt], 0, 0, 0);
            acc[jt] = __builtin_amdgcn_mfma_f32_16x16x32_bf16(a2, bfrag[2][jt], acc[jt], 0, 0, 0);
        }

        for (int jt = 0; jt < 2; ++jt) {
            for (int reg = 0; reg < 4; ++reg) {
                float h = acc[jt][reg] + bl[jt];
                if (h < 0.0f) h = 0.0f;
                int row = rt * 16 + quad * 4 + reg;
                outb[(size_t)row * STC_CH + jt * 16 + j] = __float2bfloat16(h);
            }
        }
    }
}

/* tconv2 as MFMA GEMM on transposed input: rows enumerated n*48+bt2, so the
   three A-frags are one contiguous 96-B region in node n's block. Output
   written to d_out in required (bt2, n, co) order. */
__global__ __launch_bounds__(256, 2) void stc_tconv2m(
    const bf16* Tch, const short* pk2,
    const float* B1, const float* B2, const float* B3,
    float* T2) {
    int lane = threadIdx.x & 63;
    int j = lane & 15;
    int quad = lane >> 4;
    int wave = blockIdx.x * 4 + (threadIdx.x >> 6);

    stc_s8 bfrag[3][4][3];
    for (int conv = 0; conv < 3; ++conv)
        for (int c4 = 0; c4 < 4; ++c4)
            for (int s = 0; s < 3; ++s) {
                int fi = (conv * 4 + c4) * 3 + s;
                bfrag[conv][c4][s] = *(const stc_s8*)(pk2 + (fi * 64 + lane) * 8);
            }
    float pb[4], qb[4], rb[4];
    for (int c4 = 0; c4 < 4; ++c4) {
        int och = c4 * 16 + j;
        pb[c4] = B1[och];
        qb[c4] = B2[och];
        rb[c4] = B3[och];
    }

    for (int rt = wave; rt < STC_RT2; rt += STC_GWAVE) {
        int n = rt / 3;                 /* 48 rows per node; 3 tiles per node */
        int btb = (rt % 3) * 16;
        int bt2 = btb + j;
        int b = bt2 / STC_T2;
        int t = bt2 % STC_T2;
        const bf16* ap = Tch + (size_t)n * STC_ROWB1 + (b * STC_T1 + t) * STC_CH + quad * 8;
        stc_s8 af0 = *(const stc_s8*)(ap);
        stc_s8 af1 = *(const stc_s8*)(ap + STC_CH);
        stc_s8 af2 = *(const stc_s8*)(ap + 2 * STC_CH);

        stc_f4 acc[12];
        for (int a = 0; a < 12; ++a) acc[a] = (stc_f4){0.0f, 0.0f, 0.0f, 0.0f};

        for (int conv = 0; conv < 3; ++conv) {
            for (int c4 = 0; c4 < 4; ++c4) {
                int a = conv * 4 + c4;
                acc[a] = __builtin_amdgcn_mfma_f32_16x16x32_bf16(
                    af0, bfrag[conv][c4][0], acc[a], 0, 0, 0);
                acc[a] = __builtin_amdgcn_mfma_f32_16x16x32_bf16(
                    af1, bfrag[conv][c4][1], acc[a], 0, 0, 0);
                acc[a] = __builtin_amdgcn_mfma_f32_16x16x32_bf16(
                    af2, bfrag[conv][c4][2], acc[a], 0, 0, 0);
            }
        }

        for (int c4 = 0; c4 < 4; ++c4) {
            for (int reg = 0; reg < 4; ++reg) {
                float P = acc[c4][reg] + pb[c4];
                float Q = acc[4 + c4][reg] + qb[c4];
                float R = acc[8 + c4][reg] + rb[c4];
                float Qc = fminf(fmaxf(Q, -30.0f), 30.0f);
                float sg = 1.0f / (1.0f + expf(-Qc));
                float h = P * sg + R;
                if (h < 0.0f) h = 0.0f;
                int bt2w = btb + quad * 4 + reg;
                T2[((size_t)bt2w * STC_N + n) * STC_CO + c4 * 16 + j] = h;
            }
        }
    }
}

/* per-node batch norm over (B,T,C), in-place on d_out (f32) */
__global__ void stc_bn(float* T2, const float* gamma, const float* beta) {
    int n = blockIdx.x;
    __shared__ float buf[STC_BT2 * STC_CO];
    __shared__ float red[256];
    float s = 0.0f;
    for (int i = threadIdx.x; i < STC_BT2 * STC_CO; i += 256) {
        int p = i >> 6;
        int c = i & 63;
        float v = T2[((size_t)p * STC_N + n) * STC_CO + c];
        buf[i] = v;
        s += v;
    }
    red[threadIdx.x] = s;
    __syncthreads();
    for (int off = 128; off > 0; off >>= 1) {
        if (threadIdx.x < off) red[threadIdx.x] += red[threadIdx.x + off];
        __syncthreads();
    }
    float mean = red[0] * (1.0f / (STC_BT2 * STC_CO));
    __syncthreads();
    float sq = 0.0f;
    for (int i = threadIdx.x; i < STC_BT2 * STC_CO; i += 256) {
        float d = buf[i] - mean;
        sq += d * d;
    }
    red[threadIdx.x] = sq;
    __syncthreads();
    for (int off = 128; off > 0; off >>= 1) {
        if (threadIdx.x < off) red[threadIdx.x] += red[threadIdx.x + off];
        __syncthreads();
    }
    float var = red[0] * (1.0f / (STC_BT2 * STC_CO));
    float istd = rsqrtf(var + 1e-5f);
    float scale = istd * gamma[n];
    float shift = beta[n] - mean * scale;
    for (int i = threadIdx.x; i < STC_BT2 * STC_CO; i += 256) {
        int p = i >> 6;
        int c = i & 63;
        T2[((size_t)p * STC_N + n) * STC_CO + c] = buf[i] * scale + shift;
    }
}

extern "C" void kernel_launch(void* const* d_in, const int* in_sizes, int n_in,
                              void* d_out, int out_size, void* d_ws, size_t ws_size,
                              hipStream_t stream) {
    float* out = (float*)d_out;
    int outb = (out_size + 255) / 256;

    if (n_in < 19) {
        stc_fill<<<outb, 256, 0, stream>>>(out, out_size, 60.0f);
        return;
    }
    if (ws_size < (size_t)STC_WS_REQ) {
        stc_fill<<<outb, 256, 0, stream>>>(out, out_size, 50.0f);
        return;
    }

    const float* X = (const float*)d_in[0];
    const int* ei = (const int*)d_in[1];
    const float* ew = (const float*)d_in[2];
    const float* w1a = (const float*)d_in[3];
    const float* b1a = (const float*)d_in[4];
    const float* w1b = (const float*)d_in[5];
    const float* b1b = (const float*)d_in[6];
    const float* w1c = (const float*)d_in[7];
    const float* b1c = (const float*)d_in[8];
    const float* chW = (const float*)d_in[9];
    const float* chB = (const float*)d_in[10];
    const float* w2a = (const float*)d_in[11];
    const float* b2a = (const float*)d_in[12];
    const float* w2b = (const float*)d_in[13];
    const float* b2b = (const float*)d_in[14];
    const float* w2c = (const float*)d_in[15];
    const float* b2c = (const float*)d_in[16];
    const float* gam = (const float*)d_in[17];
    const float* bet = (const float*)d_in[18];
    int E = in_sizes[1] / 2;

    char* ws = (char*)d_ws;
    float* deg = (float*)(ws + STC_OFF_DEG);
    int* cnt = (int*)(ws + STC_OFF_CNT);
    int* cursor = (int*)(ws + STC_OFF_CUR);
    float* dis = (float*)(ws + STC_OFF_DIS);
    int* offs = (int*)(ws + STC_OFF_OFFS);
    float* wn = (float*)(ws + STC_OFF_WN);
    int* ccol = (int*)(ws + STC_OFF_CCOL);
    float* cw = (float*)(ws + STC_OFF_CW);
    bf16* T0 = (bf16*)(ws + STC_OFF_T0);
    bf16* G1 = (bf16*)(ws + STC_OFF_G1);
    bf16* G2 = (bf16*)(ws + STC_OFF_G2);
    short* pk2 = (short*)(ws + STC_OFF_PK2);
    short* pk1 = (short*)(ws + STC_OFF_PK1);
    short* pkc = (short*)(ws + STC_OFF_PKC);
    bf16* Tch = T0;          /* alias: same-wave read-before-write safe */
    float* T2 = out;         /* stage tconv2 output in d_out; BN in-place */

    stc_zero<<<59, 256, 0, stream>>>((int*)(ws + STC_OFF_DEG), 15000);
    stc_pack<<<14, 256, 0, stream>>>(w1a, w1b, w1c, w2a, w2b, w2c, chW, pk1, pk2, pkc);
    stc_deg<<<(E + 255) / 256, 256, 0, stream>>>(ei, ew, deg, E);
    stc_dis<<<20, 256, 0, stream>>>(deg, dis, STC_N);
    stc_wnorm<<<(E + 255) / 256, 256, 0, stream>>>(ei, ew, dis, wn, cnt, E);
    stc_scan<<<1, 256, 0, stream>>>(cnt, offs, STC_N);
    stc_scatter<<<(E + 255) / 256, 256, 0, stream>>>(ei, wn, offs, cursor, ccol, cw, E);
    stc_tconv1m<<<STC_GBLK, 256, 0, stream>>>(X, pk1, b1a, b1b, b1c, T0);
    stc_gatherv<<<STC_N, 256, 0, stream>>>(T0, G1, offs, ccol, cw);
    stc_gatherv<<<STC_N, 256, 0, stream>>>(G1, G2, offs, ccol, cw);
    stc_combinem<<<STC_GBLK, 256, 0, stream>>>(T0, G1, G2, pkc, chB, Tch);
    stc_tconv2m<<<STC_GBLK, 256, 0, stream>>>(Tch, pk2, b2a, b2b, b2c, T2);
    stc_bn<<<STC_N, 256, 0, stream>>>(T2, gam, bet);
}